// Round 6
// baseline (1441.118 us; speedup 1.0000x reference)
//
#include <hip/hip_runtime.h>
#include <math.h>

#define NND 100000
#define TT 24
#define FI 16
#define HD 128
#define GD 384   // 3*HD
#define OD 64
#define NE 1600000

typedef __bf16 bf16x8 __attribute__((ext_vector_type(8)));
typedef float f32x4 __attribute__((ext_vector_type(4)));
typedef unsigned short u16;
typedef unsigned int u32;

__device__ __forceinline__ u16 f2b(float f) {
    u32 u = __float_as_uint(f);
    u32 r = (u + 0x7FFFu + ((u >> 16) & 1u)) >> 16;
    return (u16)r;
}
__device__ __forceinline__ u32 cvtpk(float lo, float hi) {
    u32 r;
    asm("v_cvt_pk_bf16_f32 %0, %1, %2" : "=v"(r) : "v"(lo), "v"(hi));
    return r;
}

// ---------------- transpose W[rows][cols] -> WT[cols][rows] ----------------
__global__ void transpose_kernel(const float* __restrict__ W, float* __restrict__ WT,
                                 int rows, int cols) {
    int idx = blockIdx.x * 256 + threadIdx.x;
    if (idx < rows * cols) {
        int r = idx / cols, c = idx % cols;
        WT[c * rows + r] = W[idx];
    }
}

// ---------------- x f32 -> bf16 (once) ----------------
__global__ void cvt_x_kernel(const float* __restrict__ x, u16* __restrict__ xb) {
    size_t base = ((size_t)blockIdx.x * 256 + threadIdx.x) * 8;
    float4 a = *(const float4*)(x + base);
    float4 b = *(const float4*)(x + base + 4);
    u32 o0 = cvtpk(a.x, a.y), o1 = cvtpk(a.z, a.w);
    u32 o2 = cvtpk(b.x, b.y), o3 = cvtpk(b.z, b.w);
    *(uint4*)(xb + base) = make_uint4(o0, o1, o2, o3);
}

// ---------------- pack GRU weights into MFMA A-fragments (bf16) ----------------
// Ah: lane holds row = gt*16+(lane&15), k = s*32+(lane>>4)*8..+8 of Whh[384][128]
// Ai: extended Wih' [384][32]: cols 0..15 = Wih, col 16 = bias (bih+bhh for r,z; bih for n), rest 0.
__global__ void pack_w_kernel(const float* __restrict__ Whh, const float* __restrict__ Wih,
                              const float* __restrict__ bih, const float* __restrict__ bhh,
                              u16* __restrict__ Ap, u16* __restrict__ Aip) {
    int id = blockIdx.x * 256 + threadIdx.x;
    if (id < 6144) {
        int lane = id & 63, fs = id >> 6;
        int s = fs & 3, gt = fs >> 2;
        int row = gt * 16 + (lane & 15);
        int k0 = s * 32 + (lane >> 4) * 8;
        const float* src = Whh + (size_t)row * HD + k0;
        u16 o[8];
#pragma unroll
        for (int e = 0; e < 8; ++e) o[e] = f2b(src[e]);
        u32* dst = (u32*)(Ap + (size_t)id * 8);
#pragma unroll
        for (int e = 0; e < 4; ++e) dst[e] = (u32)o[2 * e] | ((u32)o[2 * e + 1] << 16);
    } else if (id < 7680) {
        int id2 = id - 6144;
        int lane = id2 & 63, gt = id2 >> 6;
        int row = gt * 16 + (lane & 15);
        int g = lane >> 4;
        u16 o[8] = {0, 0, 0, 0, 0, 0, 0, 0};
        if (g < 2) {
            const float* src = Wih + (size_t)row * FI + g * 8;
#pragma unroll
            for (int e = 0; e < 8; ++e) o[e] = f2b(src[e]);
        } else if (g == 2) {
            float bias = (row < 2 * HD) ? (bih[row] + bhh[row]) : bih[row];
            o[0] = f2b(bias);   // k=16 column carries the bias
        }
        u32* dst = (u32*)(Aip + (size_t)id2 * 8);
#pragma unroll
        for (int e = 0; e < 4; ++e) dst[e] = (u32)o[2 * e] | ((u32)o[2 * e + 1] << 16);
    }
}

// swizzled LDS index (u16 units): row stride 128, XOR bank swizzle
__device__ __forceinline__ int hidx(int row, int col) {
    return row * 128 + (col ^ ((row & 7) << 3));
}

// ---------------- GRU via MFMA: 64 nodes / 512-thread block, 2 blocks/CU ----------------
__global__ __launch_bounds__(512, 4) void gru_mfma_kernel(
    const u16* __restrict__ xb,       // [N][T][16] bf16
    const u16* __restrict__ Ap,       // [24][4][64][8] bf16 (Whh frags)
    const u16* __restrict__ Aip,      // [24][64][8] bf16 (Wih' frags, bias in k=16)
    const float* __restrict__ bhh,
    float* __restrict__ hout)         // [N][128] f32
{
    __shared__ u16 hb0[64 * 128];
    __shared__ u16 hb1[64 * 128];

    const int tid = threadIdx.x;
    const int w = tid >> 6, lane = tid & 63;
    const int l15 = lane & 15, g = lane >> 4;
    const int gbase = blockIdx.x * 64;
    const int j0 = w * 16 + g * 4;

    for (int i = tid; i < 64 * 128 / 2; i += 512) ((u32*)hb0)[i] = 0u;

    bf16x8 Ah[3][4], Ai[3];
#pragma unroll
    for (int a = 0; a < 3; ++a) {
        int gt = w + a * 8;
#pragma unroll
        for (int s = 0; s < 4; ++s)
            Ah[a][s] = *(const bf16x8*)(Ap + ((size_t)(gt * 4 + s) * 64 + lane) * 8);
        Ai[a] = *(const bf16x8*)(Aip + ((size_t)gt * 64 + lane) * 8);
    }

    f32x4 bnh4 = *(const f32x4*)(bhh + 256 + j0);

    const f32x4 fz = {0.f, 0.f, 0.f, 0.f};
    // default x-fragment: zeros; g==2 lanes carry 1.0 at k=16 (bias column)
    bf16x8 xdef;
    {
        uint4 u = make_uint4(0u, 0u, 0u, 0u);
        if (g == 2) u.x = 0x3F80u;   // bf16 1.0 in element 0
        *(uint4*)&xdef = u;
    }

    f32x4 hreg[4];
#pragma unroll
    for (int m = 0; m < 4; ++m) hreg[m] = fz;

    int xoff[4];
#pragma unroll
    for (int m = 0; m < 4; ++m) {
        int nd = gbase + m * 16 + l15;
        nd = nd < NND ? nd : NND - 1;
        xoff[m] = nd * (TT * FI) + g * 8;
    }

    __syncthreads();

    auto dostep = [&](int t, const u16* __restrict__ rb, u16* __restrict__ wb) {
#pragma unroll
        for (int mh = 0; mh < 2; ++mh) {
            const int ma = mh * 2, mb = mh * 2 + 1;
            bf16x8 xf0 = xdef, xf1 = xdef;
            if (g < 2) {
                xf0 = *(const bf16x8*)(xb + (size_t)(xoff[ma] + t * FI));
                xf1 = *(const bf16x8*)(xb + (size_t)(xoff[mb] + t * FI));
            }

            const int ra = ma * 16 + l15, rbr = mb * 16 + l15;
            // prefetch all 8 B-fragments
            bf16x8 b0[4], b1[4];
#pragma unroll
            for (int s = 0; s < 4; ++s) {
                b0[s] = *(const bf16x8*)&rb[hidx(ra, s * 32 + g * 8)];
                b1[s] = *(const bf16x8*)&rb[hidx(rbr, s * 32 + g * 8)];
            }

            f32x4 acc[3][2], acci[2];
            __builtin_amdgcn_s_setprio(1);
#pragma unroll
            for (int a = 0; a < 3; ++a) {
                acc[a][0] = __builtin_amdgcn_mfma_f32_16x16x32_bf16(Ah[a][0], b0[0], fz, 0, 0, 0);
                acc[a][1] = __builtin_amdgcn_mfma_f32_16x16x32_bf16(Ah[a][0], b1[0], fz, 0, 0, 0);
            }
#pragma unroll
            for (int s = 1; s < 4; ++s) {
#pragma unroll
                for (int a = 0; a < 3; ++a) {
                    acc[a][0] = __builtin_amdgcn_mfma_f32_16x16x32_bf16(Ah[a][s], b0[s], acc[a][0], 0, 0, 0);
                    acc[a][1] = __builtin_amdgcn_mfma_f32_16x16x32_bf16(Ah[a][s], b1[s], acc[a][1], 0, 0, 0);
                }
            }
            // input projection + bias (k=16 column)
            acc[0][0] = __builtin_amdgcn_mfma_f32_16x16x32_bf16(Ai[0], xf0, acc[0][0], 0, 0, 0);
            acc[1][0] = __builtin_amdgcn_mfma_f32_16x16x32_bf16(Ai[1], xf0, acc[1][0], 0, 0, 0);
            acci[0]   = __builtin_amdgcn_mfma_f32_16x16x32_bf16(Ai[2], xf0, fz, 0, 0, 0);
            acc[0][1] = __builtin_amdgcn_mfma_f32_16x16x32_bf16(Ai[0], xf1, acc[0][1], 0, 0, 0);
            acc[1][1] = __builtin_amdgcn_mfma_f32_16x16x32_bf16(Ai[1], xf1, acc[1][1], 0, 0, 0);
            acci[1]   = __builtin_amdgcn_mfma_f32_16x16x32_bf16(Ai[2], xf1, fz, 0, 0, 0);
            __builtin_amdgcn_s_setprio(0);

            // gates (biases already in acc/acci) + packed bf16 write to other buffer
#pragma unroll
            for (int mi = 0; mi < 2; ++mi) {
                int m = mh * 2 + mi;
#pragma unroll
                for (int r = 0; r < 4; ++r) {
                    float rr = __builtin_amdgcn_rcpf(1.0f + __builtin_amdgcn_exp2f(acc[0][mi][r] * -1.44269504f));
                    float zz = __builtin_amdgcn_rcpf(1.0f + __builtin_amdgcn_exp2f(acc[1][mi][r] * -1.44269504f));
                    float na = acci[mi][r] + rr * (acc[2][mi][r] + bnh4[r]);
                    float nn = 1.0f - 2.0f * __builtin_amdgcn_rcpf(1.0f + __builtin_amdgcn_exp2f(na * 2.88539008f));
                    float h = nn + zz * (hreg[m][r] - nn);
                    hreg[m][r] = h;
                }
                u32 p0 = cvtpk(hreg[m][0], hreg[m][1]);
                u32 p1 = cvtpk(hreg[m][2], hreg[m][3]);
                *(uint2*)&wb[hidx(m * 16 + l15, j0)] = make_uint2(p0, p1);
            }
        }
        __syncthreads();
    };

#pragma unroll 1
    for (int tt = 0; tt < TT; tt += 2) {
        dostep(tt, hb0, hb1);
        dostep(tt + 1, hb1, hb0);
    }

#pragma unroll
    for (int m = 0; m < 4; ++m) {
        int nd = gbase + m * 16 + l15;
        if (nd < NND)
            *(f32x4*)(hout + (size_t)nd * HD + j0) = hreg[m];
    }
}

// ---------------- projection: Y[N][M] = X[N][128] @ WT (+bias) (+X residual) ----------------
template <int M, bool BIAS, bool RES>
__global__ __launch_bounds__(256) void proj_kernel(
    const float* __restrict__ X, const float* __restrict__ WT,
    const float* __restrict__ bias, float* __restrict__ Y, int n_total)
{
    constexpr int K = 128;
    constexpr int MG = M / 4;
    constexpr int NG = 256 / MG;
    constexpr int NN = 64 / NG;
    __shared__ float XT[K][68];

    const int tid = threadIdx.x;
    const int gbase = blockIdx.x * 64;

#pragma unroll
    for (int i = 0; i < 8; ++i) {
        int lin = tid + 256 * i;
        int n = lin >> 5;
        int k4 = (lin & 31) * 4;
        int gn = gbase + n; if (gn >= n_total) gn = n_total - 1;
        float4 v = *(const float4*)(X + (size_t)gn * K + k4);
        XT[k4 + 0][n] = v.x; XT[k4 + 1][n] = v.y;
        XT[k4 + 2][n] = v.z; XT[k4 + 3][n] = v.w;
    }
    __syncthreads();

    const int mg = tid % MG, ng = tid / MG;
    const int m0 = mg * 4, nb = ng * NN;
    float acc[NN][4];
#pragma unroll
    for (int a = 0; a < NN; ++a)
#pragma unroll
        for (int b = 0; b < 4; ++b) acc[a][b] = 0.f;

    for (int k = 0; k < K; ++k) {
        float4 wv4 = *(const float4*)(WT + k * M + m0);
        float wv[4] = {wv4.x, wv4.y, wv4.z, wv4.w};
        float xv[NN];
#pragma unroll
        for (int c = 0; c < NN; c += 4) {
            float4 xt = *(const float4*)&XT[k][nb + c];
            xv[c + 0] = xt.x; xv[c + 1] = xt.y; xv[c + 2] = xt.z; xv[c + 3] = xt.w;
        }
#pragma unroll
        for (int ni = 0; ni < NN; ++ni)
#pragma unroll
            for (int mm = 0; mm < 4; ++mm)
                acc[ni][mm] = fmaf(xv[ni], wv[mm], acc[ni][mm]);
    }

    float bv[4] = {0.f, 0.f, 0.f, 0.f};
    if (BIAS) { float4 b4 = *(const float4*)(bias + m0); bv[0]=b4.x; bv[1]=b4.y; bv[2]=b4.z; bv[3]=b4.w; }
#pragma unroll
    for (int ni = 0; ni < NN; ++ni) {
        int gn = gbase + nb + ni;
        if (gn < n_total) {
            float r0 = acc[ni][0] + bv[0], r1 = acc[ni][1] + bv[1];
            float r2 = acc[ni][2] + bv[2], r3 = acc[ni][3] + bv[3];
            if constexpr (RES) {
                float4 xr = *(const float4*)(X + (size_t)gn * K + m0);
                r0 += xr.x; r1 += xr.y; r2 += xr.z; r3 += xr.w;
            }
            *(float4*)(Y + (size_t)gn * M + m0) = make_float4(r0, r1, r2, r3);
        }
    }
}

// ---------------- CSR construction ----------------
__global__ void count_kernel(const int* __restrict__ dst, int* __restrict__ cnt) {
    int e = blockIdx.x * 256 + threadIdx.x;
    if (e < NE) atomicAdd(&cnt[dst[e]], 1);
}

__global__ void blocksum_kernel(const int* __restrict__ cnt, int* __restrict__ bsum) {
    __shared__ int sh[256];
    int b = blockIdx.x, t = threadIdx.x;
    int base = b * 1024;
    int s = 0;
    for (int i = t; i < 1024; i += 256) {
        int idx = base + i;
        s += (idx < NND) ? cnt[idx] : 0;
    }
    sh[t] = s; __syncthreads();
    for (int o = 128; o > 0; o >>= 1) { if (t < o) sh[t] += sh[t + o]; __syncthreads(); }
    if (t == 0) bsum[b] = sh[0];
}

__global__ void scanbsum_kernel(int* __restrict__ bsum, int nb, int* __restrict__ rowptr) {
    if (threadIdx.x == 0 && blockIdx.x == 0) {
        int acc = 0;
        for (int i = 0; i < nb; ++i) { int v = bsum[i]; bsum[i] = acc; acc += v; }
        rowptr[NND] = NE;
    }
}

__global__ void scan_kernel(const int* __restrict__ cnt, const int* __restrict__ bsum,
                            int* __restrict__ rowptr) {
    __shared__ int sh[256];
    int b = blockIdx.x, t = threadIdx.x;
    int base = b * 1024;
    int v[4], loc = 0;
#pragma unroll
    for (int j = 0; j < 4; ++j) {
        int idx = base + t * 4 + j;
        v[j] = (idx < NND) ? cnt[idx] : 0;
        loc += v[j];
    }
    sh[t] = loc; __syncthreads();
    for (int o = 1; o < 256; o <<= 1) {
        int x = (t >= o) ? sh[t - o] : 0;
        __syncthreads();
        sh[t] += x;
        __syncthreads();
    }
    int acc = bsum[b] + sh[t] - loc;
#pragma unroll
    for (int j = 0; j < 4; ++j) {
        int idx = base + t * 4 + j;
        if (idx < NND) rowptr[idx] = acc;
        acc += v[j];
    }
}

__global__ void fill_kernel(const int* __restrict__ src, const int* __restrict__ dst,
                            const int* __restrict__ rowptr, int* __restrict__ fill,
                            int* __restrict__ csr) {
    int e = blockIdx.x * 256 + threadIdx.x;
    if (e >= NE) return;
    int d = dst[e];
    int pos = rowptr[d] + atomicAdd(&fill[d], 1);
    csr[pos] = src[e];
}

// ---------------- gather-aggregate (mean) + combine, one wave per node ----------------
template <int F, bool RELU>
__global__ __launch_bounds__(256) void gather_kernel(
    const float* __restrict__ P,
    const int* __restrict__ rowptr, const int* __restrict__ csr,
    const float* __restrict__ q,
    float* __restrict__ outp)
{
    int n = ((blockIdx.x * 256 + threadIdx.x) >> 6);
    if (n >= NND) return;
    int lane = threadIdx.x & 63;
    int beg = rowptr[n], end = rowptr[n + 1];

    if constexpr (F == 128) {
        float2 acc = make_float2(0.f, 0.f);
        for (int cb = beg; cb < end; cb += 64) {
            int myi = (cb + lane < end) ? csr[cb + lane] : 0;
            int nn = min(end - cb, 64);
            for (int i = 0; i < nn; ++i) {
                int s = __shfl(myi, i);
                float2 v = *(const float2*)(P + (size_t)s * F + lane * 2);
                acc.x += v.x; acc.y += v.y;
            }
        }
        int deg = end - beg;
        float inv = 1.0f / (float)(deg > 0 ? deg : 1);
        float2 qv = *(const float2*)(q + (size_t)n * F + lane * 2);
        float r0 = acc.x * inv + qv.x, r1 = acc.y * inv + qv.y;
        if (RELU) { r0 = fmaxf(r0, 0.f); r1 = fmaxf(r1, 0.f); }
        *(float2*)(outp + (size_t)n * F + lane * 2) = make_float2(r0, r1);
    } else {
        float acc = 0.f;
        for (int cb = beg; cb < end; cb += 64) {
            int myi = (cb + lane < end) ? csr[cb + lane] : 0;
            int nn = min(end - cb, 64);
            for (int i = 0; i < nn; ++i) {
                int s = __shfl(myi, i);
                acc += P[(size_t)s * F + lane];
            }
        }
        int deg = end - beg;
        float inv = 1.0f / (float)(deg > 0 ? deg : 1);
        float r = acc * inv + q[(size_t)n * F + lane];
        if (RELU) r = fmaxf(r, 0.f);
        outp[(size_t)n * F + lane] = r;
    }
}

// ---------------- launch ----------------
extern "C" void kernel_launch(void* const* d_in, const int* in_sizes, int n_in,
                              void* d_out, int out_size, void* d_ws, size_t ws_size,
                              hipStream_t stream) {
    const float* x   = (const float*)d_in[0];
    const int*   edg = (const int*)d_in[1];
    const int*   src = edg;
    const int*   dst = edg + NE;
    const float* Wih = (const float*)d_in[2];
    const float* Whh = (const float*)d_in[3];
    const float* bih = (const float*)d_in[4];
    const float* bhh = (const float*)d_in[5];
    const float* W1l = (const float*)d_in[6];
    const float* b1  = (const float*)d_in[7];
    const float* W1r = (const float*)d_in[8];
    const float* W2l = (const float*)d_in[9];
    const float* b2  = (const float*)d_in[10];
    const float* W2r = (const float*)d_in[11];
    float* out = (float*)d_out;

    char* wsp = (char*)d_ws;
    auto alloc = [&](size_t nbytes) {
        char* p = wsp; wsp += (nbytes + 255) & ~(size_t)255; return p;
    };
    u16*   Ap    = (u16*)alloc((size_t)6144 * 8 * 2);
    u16*   Aip   = (u16*)alloc((size_t)1536 * 8 * 2);
    float* WT1l  = (float*)alloc((size_t)HD * HD * 4);
    float* WT1r  = (float*)alloc((size_t)HD * HD * 4);
    float* WT2l  = (float*)alloc((size_t)HD * OD * 4);
    float* WT2r  = (float*)alloc((size_t)HD * OD * 4);
    int*   cnt   = (int*)alloc((size_t)NND * 4);
    int*   fill  = (int*)alloc((size_t)NND * 4);
    int*   rowp  = (int*)alloc((size_t)(NND + 1) * 4);
    int*   bsum  = (int*)alloc((size_t)128 * 4);
    int*   csr   = (int*)alloc((size_t)NE * 4);
    float* h     = (float*)alloc((size_t)NND * HD * 4);
    float* p     = (float*)alloc((size_t)NND * HD * 4);
    float* q     = (float*)alloc((size_t)NND * HD * 4);
    float* g     = (float*)alloc((size_t)NND * HD * 4);
    // xb ([N][T][16] bf16 = 76.8 MB) aliases q+g (102.4 MB): xb is consumed by
    // the GRU before q or g are first written (same stream -> ordered).
    u16*   xb    = (u16*)q;

    const int NB_SCAN = (NND + 1023) / 1024;

    hipMemsetAsync(cnt, 0, (size_t)NND * 4, stream);
    hipMemsetAsync(fill, 0, (size_t)NND * 4, stream);

    // prep
    cvt_x_kernel<<<(NND * TT * FI) / (256 * 8), 256, 0, stream>>>(x, xb);
    pack_w_kernel<<<30, 256, 0, stream>>>(Whh, Wih, bih, bhh, Ap, Aip);
    transpose_kernel<<<(HD * HD + 255) / 256, 256, 0, stream>>>(W1l, WT1l, HD, HD);
    transpose_kernel<<<(HD * HD + 255) / 256, 256, 0, stream>>>(W1r, WT1r, HD, HD);
    transpose_kernel<<<(OD * HD + 255) / 256, 256, 0, stream>>>(W2l, WT2l, OD, HD);
    transpose_kernel<<<(OD * HD + 255) / 256, 256, 0, stream>>>(W2r, WT2r, OD, HD);

    // CSR build
    count_kernel<<<(NE + 255) / 256, 256, 0, stream>>>(dst, cnt);
    blocksum_kernel<<<NB_SCAN, 256, 0, stream>>>(cnt, bsum);
    scanbsum_kernel<<<1, 64, 0, stream>>>(bsum, NB_SCAN, rowp);
    scan_kernel<<<NB_SCAN, 256, 0, stream>>>(cnt, bsum, rowp);
    fill_kernel<<<(NE + 255) / 256, 256, 0, stream>>>(src, dst, rowp, fill, csr);

    // GRU -> h [N,128]  (64 nodes/block, 2 blocks/CU target)
    const int nblk_gru = (NND + 63) / 64;
    gru_mfma_kernel<<<nblk_gru, 512, 0, stream>>>(xb, Ap, Aip, bhh, h);

    // layer 1: project, then mean-gather (+q, relu) fused
    const int nblk = (NND + 63) / 64;
    proj_kernel<HD, false, false><<<nblk, 256, 0, stream>>>(h, WT1l, nullptr, p, NND);
    proj_kernel<HD, true,  true ><<<nblk, 256, 0, stream>>>(h, WT1r, b1, q, NND);
    gather_kernel<HD, true><<<(NND * 64 + 255) / 256, 256, 0, stream>>>(p, rowp, csr, q, g);

    // layer 2: project to 64, then mean-gather (+q)
    proj_kernel<OD, false, false><<<nblk, 256, 0, stream>>>(g, WT2l, nullptr, p, NND);
    proj_kernel<OD, true,  false><<<nblk, 256, 0, stream>>>(g, WT2r, b2, q, NND);
    gather_kernel<OD, false><<<(NND * 64 + 255) / 256, 256, 0, stream>>>(p, rowp, csr, q, out);
}

// Round 7
// 967.095 us; speedup vs baseline: 1.4902x; 1.4902x over previous
//
#include <hip/hip_runtime.h>
#include <math.h>

#define NND 100000
#define TT 24
#define FI 16
#define HD 128
#define GD 384   // 3*HD
#define OD 64
#define NE 1600000

typedef __bf16 bf16x8 __attribute__((ext_vector_type(8)));
typedef float f32x4 __attribute__((ext_vector_type(4)));
typedef unsigned short u16;
typedef unsigned int u32;

#define S_RZ (-1.44269504f)   // -log2(e): sigmoid via rcp(1+exp2(s*a))
#define S_N  (-2.88539008f)   // -2*log2(e): tanh via 2*rcp(1+exp2(s*a))-1

__device__ __forceinline__ u16 f2b(float f) {
    u32 u = __float_as_uint(f);
    u32 r = (u + 0x7FFFu + ((u >> 16) & 1u)) >> 16;
    return (u16)r;
}
__device__ __forceinline__ u32 cvtpk(float lo, float hi) {
    u32 r;
    asm("v_cvt_pk_bf16_f32 %0, %1, %2" : "=v"(r) : "v"(lo), "v"(hi));
    return r;
}

// ---------------- transpose W[rows][cols] -> WT[cols][rows] ----------------
__global__ void transpose_kernel(const float* __restrict__ W, float* __restrict__ WT,
                                 int rows, int cols) {
    int idx = blockIdx.x * 256 + threadIdx.x;
    if (idx < rows * cols) {
        int r = idx / cols, c = idx % cols;
        WT[c * rows + r] = W[idx];
    }
}

// ---------------- x f32 -> bf16 (once) ----------------
__global__ void cvt_x_kernel(const float* __restrict__ x, u16* __restrict__ xb) {
    size_t base = ((size_t)blockIdx.x * 256 + threadIdx.x) * 8;
    float4 a = *(const float4*)(x + base);
    float4 b = *(const float4*)(x + base + 4);
    u32 o0 = cvtpk(a.x, a.y), o1 = cvtpk(a.z, a.w);
    u32 o2 = cvtpk(b.x, b.y), o3 = cvtpk(b.z, b.w);
    *(uint4*)(xb + base) = make_uint4(o0, o1, o2, o3);
}

// ---------------- pack GRU weights into MFMA A-fragments (bf16, scale-folded) ----------------
// rows [0,256): r,z gates scaled by S_RZ; rows [256,384): n gate scaled by S_N.
// Ai extended [384][32]: cols 0..15 = Wih*s, col 16 = bias*s (bih+bhh for r,z; bih for n).
__global__ void pack_w_kernel(const float* __restrict__ Whh, const float* __restrict__ Wih,
                              const float* __restrict__ bih, const float* __restrict__ bhh,
                              u16* __restrict__ Ap, u16* __restrict__ Aip) {
    int id = blockIdx.x * 256 + threadIdx.x;
    if (id < 6144) {
        int lane = id & 63, fs = id >> 6;
        int s = fs & 3, gt = fs >> 2;
        int row = gt * 16 + (lane & 15);
        float sc = (row < 2 * HD) ? S_RZ : S_N;
        int k0 = s * 32 + (lane >> 4) * 8;
        const float* src = Whh + (size_t)row * HD + k0;
        u16 o[8];
#pragma unroll
        for (int e = 0; e < 8; ++e) o[e] = f2b(src[e] * sc);
        u32* dst = (u32*)(Ap + (size_t)id * 8);
#pragma unroll
        for (int e = 0; e < 4; ++e) dst[e] = (u32)o[2 * e] | ((u32)o[2 * e + 1] << 16);
    } else if (id < 7680) {
        int id2 = id - 6144;
        int lane = id2 & 63, gt = id2 >> 6;
        int row = gt * 16 + (lane & 15);
        float sc = (row < 2 * HD) ? S_RZ : S_N;
        int g = lane >> 4;
        u16 o[8] = {0, 0, 0, 0, 0, 0, 0, 0};
        if (g < 2) {
            const float* src = Wih + (size_t)row * FI + g * 8;
#pragma unroll
            for (int e = 0; e < 8; ++e) o[e] = f2b(src[e] * sc);
        } else if (g == 2) {
            float bias = (row < 2 * HD) ? (bih[row] + bhh[row]) : bih[row];
            o[0] = f2b(bias * sc);   // k=16 column carries the scaled bias
        }
        u32* dst = (u32*)(Aip + (size_t)id2 * 8);
#pragma unroll
        for (int e = 0; e < 4; ++e) dst[e] = (u32)o[2 * e] | ((u32)o[2 * e + 1] << 16);
    }
}

// swizzled LDS index (u16 units): row stride 128, XOR bank swizzle
__device__ __forceinline__ int hidx(int row, int col) {
    return row * 128 + (col ^ ((row & 7) << 3));
}

// ---------------- GRU via MFMA: 64 nodes / 512-thread block ----------------
__global__ __launch_bounds__(512) void gru_mfma_kernel(
    const u16* __restrict__ xb,       // [N][T][16] bf16
    const u16* __restrict__ Ap,       // [24][4][64][8] bf16 (Whh frags, scaled)
    const u16* __restrict__ Aip,      // [24][64][8] bf16 (Wih' frags, scaled, bias k=16)
    const float* __restrict__ bhh,
    float* __restrict__ hout)         // [N][128] f32
{
    __shared__ u16 hb0[64 * 128];
    __shared__ u16 hb1[64 * 128];

    const int tid = threadIdx.x;
    const int w = tid >> 6, lane = tid & 63;
    const int l15 = lane & 15, g = lane >> 4;
    const int gbase = blockIdx.x * 64;
    const int j0 = w * 16 + g * 4;

    for (int i = tid; i < 64 * 128 / 2; i += 512) ((u32*)hb0)[i] = 0u;

    bf16x8 Ah[3][4], Ai[3];
#pragma unroll
    for (int a = 0; a < 3; ++a) {
        int gt = w + a * 8;
#pragma unroll
        for (int s = 0; s < 4; ++s)
            Ah[a][s] = *(const bf16x8*)(Ap + ((size_t)(gt * 4 + s) * 64 + lane) * 8);
        Ai[a] = *(const bf16x8*)(Aip + ((size_t)gt * 64 + lane) * 8);
    }

    f32x4 bnh4 = *(const f32x4*)(bhh + 256 + j0);
#pragma unroll
    for (int r = 0; r < 4; ++r) bnh4[r] *= S_N;   // scaled to match folded n rows

    const f32x4 fz = {0.f, 0.f, 0.f, 0.f};
    bf16x8 xdef;
    {
        uint4 u = make_uint4(0u, 0u, 0u, 0u);
        if (g == 2) u.x = 0x3F80u;   // bf16 1.0 at k=16 (bias column)
        *(uint4*)&xdef = u;
    }

    f32x4 hreg[4];
#pragma unroll
    for (int m = 0; m < 4; ++m) hreg[m] = fz;

    int xoff[4];
#pragma unroll
    for (int m = 0; m < 4; ++m) {
        int nd = gbase + m * 16 + l15;
        nd = nd < NND ? nd : NND - 1;
        xoff[m] = nd * (TT * FI) + g * 8;
    }

    __syncthreads();

    auto dostep = [&](int t, const u16* __restrict__ rb, u16* __restrict__ wb) {
#pragma unroll
        for (int mh = 0; mh < 2; ++mh) {
            const int ma = mh * 2, mb = mh * 2 + 1;
            bf16x8 xf0 = xdef, xf1 = xdef;
            if (g < 2) {
                xf0 = *(const bf16x8*)(xb + (size_t)(xoff[ma] + t * FI));
                xf1 = *(const bf16x8*)(xb + (size_t)(xoff[mb] + t * FI));
            }

            const int ra = ma * 16 + l15, rbr = mb * 16 + l15;
            bf16x8 b0[4], b1[4];
#pragma unroll
            for (int s = 0; s < 4; ++s) {
                b0[s] = *(const bf16x8*)&rb[hidx(ra, s * 32 + g * 8)];
                b1[s] = *(const bf16x8*)&rb[hidx(rbr, s * 32 + g * 8)];
            }

            f32x4 acc[3][2], acci[2];
#pragma unroll
            for (int a = 0; a < 3; ++a) {
                acc[a][0] = __builtin_amdgcn_mfma_f32_16x16x32_bf16(Ah[a][0], b0[0], fz, 0, 0, 0);
                acc[a][1] = __builtin_amdgcn_mfma_f32_16x16x32_bf16(Ah[a][0], b1[0], fz, 0, 0, 0);
            }
#pragma unroll
            for (int s = 1; s < 4; ++s) {
#pragma unroll
                for (int a = 0; a < 3; ++a) {
                    acc[a][0] = __builtin_amdgcn_mfma_f32_16x16x32_bf16(Ah[a][s], b0[s], acc[a][0], 0, 0, 0);
                    acc[a][1] = __builtin_amdgcn_mfma_f32_16x16x32_bf16(Ah[a][s], b1[s], acc[a][1], 0, 0, 0);
                }
            }
            acc[0][0] = __builtin_amdgcn_mfma_f32_16x16x32_bf16(Ai[0], xf0, acc[0][0], 0, 0, 0);
            acc[1][0] = __builtin_amdgcn_mfma_f32_16x16x32_bf16(Ai[1], xf0, acc[1][0], 0, 0, 0);
            acci[0]   = __builtin_amdgcn_mfma_f32_16x16x32_bf16(Ai[2], xf0, fz, 0, 0, 0);
            acc[0][1] = __builtin_amdgcn_mfma_f32_16x16x32_bf16(Ai[0], xf1, acc[0][1], 0, 0, 0);
            acc[1][1] = __builtin_amdgcn_mfma_f32_16x16x32_bf16(Ai[1], xf1, acc[1][1], 0, 0, 0);
            acci[1]   = __builtin_amdgcn_mfma_f32_16x16x32_bf16(Ai[2], xf1, fz, 0, 0, 0);

            // gates: scales/biases pre-folded into acc
#pragma unroll
            for (int mi = 0; mi < 2; ++mi) {
                int m = mh * 2 + mi;
#pragma unroll
                for (int r = 0; r < 4; ++r) {
                    float rr = __builtin_amdgcn_rcpf(1.0f + __builtin_amdgcn_exp2f(acc[0][mi][r]));
                    float zz = __builtin_amdgcn_rcpf(1.0f + __builtin_amdgcn_exp2f(acc[1][mi][r]));
                    float na = acci[mi][r] + rr * (acc[2][mi][r] + bnh4[r]);
                    float nn = 2.0f * __builtin_amdgcn_rcpf(1.0f + __builtin_amdgcn_exp2f(na)) - 1.0f;
                    float h = nn + zz * (hreg[m][r] - nn);
                    hreg[m][r] = h;
                }
                u32 p0 = cvtpk(hreg[m][0], hreg[m][1]);
                u32 p1 = cvtpk(hreg[m][2], hreg[m][3]);
                *(uint2*)&wb[hidx(m * 16 + l15, j0)] = make_uint2(p0, p1);
            }
        }
        __syncthreads();
    };

#pragma unroll 1
    for (int tt = 0; tt < TT; tt += 2) {
        dostep(tt, hb0, hb1);
        dostep(tt + 1, hb1, hb0);
    }

#pragma unroll
    for (int m = 0; m < 4; ++m) {
        int nd = gbase + m * 16 + l15;
        if (nd < NND)
            *(f32x4*)(hout + (size_t)nd * HD + j0) = hreg[m];
    }
}

// ---------------- fused dual projection: P = X@WTl, Q = X@WTr + b (+X res) ----------------
template <int M, bool RES>
__global__ __launch_bounds__(256) void proj2_kernel(
    const float* __restrict__ X,     // [N][128]
    const float* __restrict__ WTl,   // [128][M]
    const float* __restrict__ WTr,   // [128][M]
    const float* __restrict__ bias,  // [M]
    float* __restrict__ P, float* __restrict__ Q, int n_total)
{
    constexpr int K = 128;
    constexpr int MG = M / 4;
    constexpr int NG = 256 / MG;
    constexpr int NN = 64 / NG;
    __shared__ float XT[K][68];

    const int tid = threadIdx.x;
    const int gbase = blockIdx.x * 64;

#pragma unroll
    for (int i = 0; i < 8; ++i) {
        int lin = tid + 256 * i;
        int n = lin >> 5;
        int k4 = (lin & 31) * 4;
        int gn = gbase + n; if (gn >= n_total) gn = n_total - 1;
        float4 v = *(const float4*)(X + (size_t)gn * K + k4);
        XT[k4 + 0][n] = v.x; XT[k4 + 1][n] = v.y;
        XT[k4 + 2][n] = v.z; XT[k4 + 3][n] = v.w;
    }
    __syncthreads();

    const int mg = tid % MG, ng = tid / MG;
    const int m0 = mg * 4, nb = ng * NN;
    float accp[NN][4], accq[NN][4];
#pragma unroll
    for (int a = 0; a < NN; ++a)
#pragma unroll
        for (int b = 0; b < 4; ++b) { accp[a][b] = 0.f; accq[a][b] = 0.f; }

    for (int k = 0; k < K; ++k) {
        float4 wl4 = *(const float4*)(WTl + k * M + m0);
        float4 wr4 = *(const float4*)(WTr + k * M + m0);
        float wl[4] = {wl4.x, wl4.y, wl4.z, wl4.w};
        float wr[4] = {wr4.x, wr4.y, wr4.z, wr4.w};
        float xv[NN];
#pragma unroll
        for (int c = 0; c < NN; c += 4) {
            float4 xt = *(const float4*)&XT[k][nb + c];
            xv[c + 0] = xt.x; xv[c + 1] = xt.y; xv[c + 2] = xt.z; xv[c + 3] = xt.w;
        }
#pragma unroll
        for (int ni = 0; ni < NN; ++ni)
#pragma unroll
            for (int mm = 0; mm < 4; ++mm) {
                accp[ni][mm] = fmaf(xv[ni], wl[mm], accp[ni][mm]);
                accq[ni][mm] = fmaf(xv[ni], wr[mm], accq[ni][mm]);
            }
    }

    float4 b4 = *(const float4*)(bias + m0);
    float bv[4] = {b4.x, b4.y, b4.z, b4.w};
#pragma unroll
    for (int ni = 0; ni < NN; ++ni) {
        int gn = gbase + nb + ni;
        if (gn < n_total) {
            *(float4*)(P + (size_t)gn * M + m0) =
                make_float4(accp[ni][0], accp[ni][1], accp[ni][2], accp[ni][3]);
            float r0 = accq[ni][0] + bv[0], r1 = accq[ni][1] + bv[1];
            float r2 = accq[ni][2] + bv[2], r3 = accq[ni][3] + bv[3];
            if constexpr (RES) {
                float4 xr = *(const float4*)(X + (size_t)gn * K + m0);
                r0 += xr.x; r1 += xr.y; r2 += xr.z; r3 += xr.w;
            }
            *(float4*)(Q + (size_t)gn * M + m0) = make_float4(r0, r1, r2, r3);
        }
    }
}

// ---------------- CSR construction ----------------
__global__ void count_kernel(const int* __restrict__ dst, int* __restrict__ cnt) {
    int e = blockIdx.x * 256 + threadIdx.x;
    if (e < NE) atomicAdd(&cnt[dst[e]], 1);
}

__global__ void blocksum_kernel(const int* __restrict__ cnt, int* __restrict__ bsum) {
    __shared__ int sh[256];
    int b = blockIdx.x, t = threadIdx.x;
    int base = b * 1024;
    int s = 0;
    for (int i = t; i < 1024; i += 256) {
        int idx = base + i;
        s += (idx < NND) ? cnt[idx] : 0;
    }
    sh[t] = s; __syncthreads();
    for (int o = 128; o > 0; o >>= 1) { if (t < o) sh[t] += sh[t + o]; __syncthreads(); }
    if (t == 0) bsum[b] = sh[0];
}

__global__ void scanbsum_kernel(int* __restrict__ bsum, int nb, int* __restrict__ rowptr) {
    if (threadIdx.x == 0 && blockIdx.x == 0) {
        int acc = 0;
        for (int i = 0; i < nb; ++i) { int v = bsum[i]; bsum[i] = acc; acc += v; }
        rowptr[NND] = NE;
    }
}

__global__ void scan_kernel(const int* __restrict__ cnt, const int* __restrict__ bsum,
                            int* __restrict__ rowptr) {
    __shared__ int sh[256];
    int b = blockIdx.x, t = threadIdx.x;
    int base = b * 1024;
    int v[4], loc = 0;
#pragma unroll
    for (int j = 0; j < 4; ++j) {
        int idx = base + t * 4 + j;
        v[j] = (idx < NND) ? cnt[idx] : 0;
        loc += v[j];
    }
    sh[t] = loc; __syncthreads();
    for (int o = 1; o < 256; o <<= 1) {
        int x = (t >= o) ? sh[t - o] : 0;
        __syncthreads();
        sh[t] += x;
        __syncthreads();
    }
    int acc = bsum[b] + sh[t] - loc;
#pragma unroll
    for (int j = 0; j < 4; ++j) {
        int idx = base + t * 4 + j;
        if (idx < NND) rowptr[idx] = acc;
        acc += v[j];
    }
}

__global__ void fill_kernel(const int* __restrict__ src, const int* __restrict__ dst,
                            const int* __restrict__ rowptr, int* __restrict__ fill,
                            int* __restrict__ csr) {
    int e = blockIdx.x * 256 + threadIdx.x;
    if (e >= NE) return;
    int d = dst[e];
    int pos = rowptr[d] + atomicAdd(&fill[d], 1);
    csr[pos] = src[e];
}

// ---------------- gather-aggregate (mean) + combine, one wave per node ----------------
template <int F, bool RELU>
__global__ __launch_bounds__(256) void gather_kernel(
    const float* __restrict__ P,
    const int* __restrict__ rowptr, const int* __restrict__ csr,
    const float* __restrict__ q,
    float* __restrict__ outp)
{
    int n = ((blockIdx.x * 256 + threadIdx.x) >> 6);
    if (n >= NND) return;
    int lane = threadIdx.x & 63;
    int beg = rowptr[n], end = rowptr[n + 1];

    if constexpr (F == 128) {
        float2 acc = make_float2(0.f, 0.f);
        for (int cb = beg; cb < end; cb += 64) {
            int myi = (cb + lane < end) ? csr[cb + lane] : 0;
            int nn = min(end - cb, 64);
            for (int i = 0; i < nn; ++i) {
                int s = __shfl(myi, i);
                float2 v = *(const float2*)(P + (size_t)s * F + lane * 2);
                acc.x += v.x; acc.y += v.y;
            }
        }
        int deg = end - beg;
        float inv = 1.0f / (float)(deg > 0 ? deg : 1);
        float2 qv = *(const float2*)(q + (size_t)n * F + lane * 2);
        float r0 = acc.x * inv + qv.x, r1 = acc.y * inv + qv.y;
        if (RELU) { r0 = fmaxf(r0, 0.f); r1 = fmaxf(r1, 0.f); }
        *(float2*)(outp + (size_t)n * F + lane * 2) = make_float2(r0, r1);
    } else {
        float acc = 0.f;
        for (int cb = beg; cb < end; cb += 64) {
            int myi = (cb + lane < end) ? csr[cb + lane] : 0;
            int nn = min(end - cb, 64);
            for (int i = 0; i < nn; ++i) {
                int s = __shfl(myi, i);
                acc += P[(size_t)s * F + lane];
            }
        }
        int deg = end - beg;
        float inv = 1.0f / (float)(deg > 0 ? deg : 1);
        float r = acc * inv + q[(size_t)n * F + lane];
        if (RELU) r = fmaxf(r, 0.f);
        outp[(size_t)n * F + lane] = r;
    }
}

// ---------------- launch ----------------
extern "C" void kernel_launch(void* const* d_in, const int* in_sizes, int n_in,
                              void* d_out, int out_size, void* d_ws, size_t ws_size,
                              hipStream_t stream) {
    const float* x   = (const float*)d_in[0];
    const int*   edg = (const int*)d_in[1];
    const int*   src = edg;
    const int*   dst = edg + NE;
    const float* Wih = (const float*)d_in[2];
    const float* Whh = (const float*)d_in[3];
    const float* bih = (const float*)d_in[4];
    const float* bhh = (const float*)d_in[5];
    const float* W1l = (const float*)d_in[6];
    const float* b1  = (const float*)d_in[7];
    const float* W1r = (const float*)d_in[8];
    const float* W2l = (const float*)d_in[9];
    const float* b2  = (const float*)d_in[10];
    const float* W2r = (const float*)d_in[11];
    float* out = (float*)d_out;

    char* wsp = (char*)d_ws;
    auto alloc = [&](size_t nbytes) {
        char* p = wsp; wsp += (nbytes + 255) & ~(size_t)255; return p;
    };
    u16*   Ap    = (u16*)alloc((size_t)6144 * 8 * 2);
    u16*   Aip   = (u16*)alloc((size_t)1536 * 8 * 2);
    float* WT1l  = (float*)alloc((size_t)HD * HD * 4);
    float* WT1r  = (float*)alloc((size_t)HD * HD * 4);
    float* WT2l  = (float*)alloc((size_t)HD * OD * 4);
    float* WT2r  = (float*)alloc((size_t)HD * OD * 4);
    int*   cnt   = (int*)alloc((size_t)NND * 4);
    int*   fill  = (int*)alloc((size_t)NND * 4);
    int*   rowp  = (int*)alloc((size_t)(NND + 1) * 4);
    int*   bsum  = (int*)alloc((size_t)128 * 4);
    int*   csr   = (int*)alloc((size_t)NE * 4);
    float* h     = (float*)alloc((size_t)NND * HD * 4);
    float* p     = (float*)alloc((size_t)NND * HD * 4);
    float* q     = (float*)alloc((size_t)NND * HD * 4);
    float* g     = (float*)alloc((size_t)NND * HD * 4);
    // xb ([N][T][16] bf16 = 76.8 MB) aliases q+g (102.4 MB): consumed by GRU
    // before q or g are first written (same stream -> ordered).
    u16*   xb    = (u16*)q;

    const int NB_SCAN = (NND + 1023) / 1024;

    hipMemsetAsync(cnt, 0, (size_t)NND * 4, stream);
    hipMemsetAsync(fill, 0, (size_t)NND * 4, stream);

    // prep
    cvt_x_kernel<<<(NND * TT * FI) / (256 * 8), 256, 0, stream>>>(x, xb);
    pack_w_kernel<<<30, 256, 0, stream>>>(Whh, Wih, bih, bhh, Ap, Aip);
    transpose_kernel<<<(HD * HD + 255) / 256, 256, 0, stream>>>(W1l, WT1l, HD, HD);
    transpose_kernel<<<(HD * HD + 255) / 256, 256, 0, stream>>>(W1r, WT1r, HD, HD);
    transpose_kernel<<<(OD * HD + 255) / 256, 256, 0, stream>>>(W2l, WT2l, OD, HD);
    transpose_kernel<<<(OD * HD + 255) / 256, 256, 0, stream>>>(W2r, WT2r, OD, HD);

    // CSR build
    count_kernel<<<(NE + 255) / 256, 256, 0, stream>>>(dst, cnt);
    blocksum_kernel<<<NB_SCAN, 256, 0, stream>>>(cnt, bsum);
    scanbsum_kernel<<<1, 64, 0, stream>>>(bsum, NB_SCAN, rowp);
    scan_kernel<<<NB_SCAN, 256, 0, stream>>>(cnt, bsum, rowp);
    fill_kernel<<<(NE + 255) / 256, 256, 0, stream>>>(src, dst, rowp, fill, csr);

    // GRU -> h [N,128]
    const int nblk = (NND + 63) / 64;
    gru_mfma_kernel<<<nblk, 512, 0, stream>>>(xb, Ap, Aip, bhh, h);

    // layer 1: fused dual projection, then mean-gather (+q, relu)
    proj2_kernel<HD, true><<<nblk, 256, 0, stream>>>(h, WT1l, WT1r, b1, p, q, NND);
    gather_kernel<HD, true><<<(NND * 64 + 255) / 256, 256, 0, stream>>>(p, rowp, csr, q, g);

    // layer 2: fused dual projection to 64, then mean-gather (+q)
    proj2_kernel<OD, false><<<nblk, 256, 0, stream>>>(g, WT2l, WT2r, b2, p, q, NND);
    gather_kernel<OD, false><<<(NND * 64 + 255) / 256, 256, 0, stream>>>(p, rowp, csr, q, out);
}

// Round 8
// 850.247 us; speedup vs baseline: 1.6949x; 1.1374x over previous
//
#include <hip/hip_runtime.h>
#include <math.h>

#define NND 100000
#define TT 24
#define FI 16
#define HD 128
#define GD 384   // 3*HD
#define OD 64
#define NE 1600000

typedef __bf16 bf16x8 __attribute__((ext_vector_type(8)));
typedef float f32x4 __attribute__((ext_vector_type(4)));
typedef unsigned short u16;
typedef unsigned int u32;

#define S_RZ (-1.44269504f)   // -log2(e): sigmoid via rcp(1+exp2(s*a))
#define S_N  (-2.88539008f)   // -2*log2(e): tanh via 2*rcp(1+exp2(s*a))-1

__device__ __forceinline__ u16 f2b(float f) {
    u32 u = __float_as_uint(f);
    u32 r = (u + 0x7FFFu + ((u >> 16) & 1u)) >> 16;
    return (u16)r;
}
__device__ __forceinline__ u32 cvtpk(float lo, float hi) {
    u32 r;
    asm("v_cvt_pk_bf16_f32 %0, %1, %2" : "=v"(r) : "v"(lo), "v"(hi));
    return r;
}
__device__ __forceinline__ float b2f(u16 v) {
    return __uint_as_float((u32)v << 16);
}

// ---------------- x f32 -> bf16 (once) ----------------
__global__ void cvt_x_kernel(const float* __restrict__ x, u16* __restrict__ xb) {
    size_t base = ((size_t)blockIdx.x * 256 + threadIdx.x) * 8;
    float4 a = *(const float4*)(x + base);
    float4 b = *(const float4*)(x + base + 4);
    u32 o0 = cvtpk(a.x, a.y), o1 = cvtpk(a.z, a.w);
    u32 o2 = cvtpk(b.x, b.y), o3 = cvtpk(b.z, b.w);
    *(uint4*)(xb + base) = make_uint4(o0, o1, o2, o3);
}

// ---------------- pack GRU weights into MFMA A-fragments (bf16, scale-folded) ----------------
__global__ void pack_w_kernel(const float* __restrict__ Whh, const float* __restrict__ Wih,
                              const float* __restrict__ bih, const float* __restrict__ bhh,
                              u16* __restrict__ Ap, u16* __restrict__ Aip) {
    int id = blockIdx.x * 256 + threadIdx.x;
    if (id < 6144) {
        int lane = id & 63, fs = id >> 6;
        int s = fs & 3, gt = fs >> 2;
        int row = gt * 16 + (lane & 15);
        float sc = (row < 2 * HD) ? S_RZ : S_N;
        int k0 = s * 32 + (lane >> 4) * 8;
        const float* src = Whh + (size_t)row * HD + k0;
        u16 o[8];
#pragma unroll
        for (int e = 0; e < 8; ++e) o[e] = f2b(src[e] * sc);
        u32* dst = (u32*)(Ap + (size_t)id * 8);
#pragma unroll
        for (int e = 0; e < 4; ++e) dst[e] = (u32)o[2 * e] | ((u32)o[2 * e + 1] << 16);
    } else if (id < 7680) {
        int id2 = id - 6144;
        int lane = id2 & 63, gt = id2 >> 6;
        int row = gt * 16 + (lane & 15);
        float sc = (row < 2 * HD) ? S_RZ : S_N;
        int g = lane >> 4;
        u16 o[8] = {0, 0, 0, 0, 0, 0, 0, 0};
        if (g < 2) {
            const float* src = Wih + (size_t)row * FI + g * 8;
#pragma unroll
            for (int e = 0; e < 8; ++e) o[e] = f2b(src[e] * sc);
        } else if (g == 2) {
            float bias = (row < 2 * HD) ? (bih[row] + bhh[row]) : bih[row];
            o[0] = f2b(bias * sc);
        }
        u32* dst = (u32*)(Aip + (size_t)id2 * 8);
#pragma unroll
        for (int e = 0; e < 4; ++e) dst[e] = (u32)o[2 * e] | ((u32)o[2 * e + 1] << 16);
    }
}

// ---------------- pack GEMM weight W[rows][128] into A-frags ----------------
__global__ void pack_gemm_kernel(const float* __restrict__ W, u16* __restrict__ F, int rows) {
    int id = blockIdx.x * 256 + threadIdx.x;
    if (id >= rows * 16) return;
    int lane = id & 63, fs = id >> 6;
    int s = fs & 3, tile = fs >> 2;
    int row = tile * 16 + (lane & 15);
    int k0 = s * 32 + (lane >> 4) * 8;
    const float* src = W + (size_t)row * HD + k0;
    u16 o[8];
#pragma unroll
    for (int e = 0; e < 8; ++e) o[e] = f2b(src[e]);
    u32* dst = (u32*)(F + (size_t)id * 8);
#pragma unroll
    for (int e = 0; e < 4; ++e) dst[e] = (u32)o[2 * e] | ((u32)o[2 * e + 1] << 16);
}

// swizzled LDS index (u16 units): row stride 128, XOR bank swizzle
__device__ __forceinline__ int hidx(int row, int col) {
    return row * 128 + (col ^ ((row & 7) << 3));
}

// ---------------- GRU via MFMA: 64 nodes / 512-thread block ----------------
__global__ __launch_bounds__(512) void gru_mfma_kernel(
    const u16* __restrict__ xb,
    const u16* __restrict__ Ap,
    const u16* __restrict__ Aip,
    const float* __restrict__ bhh,
    float* __restrict__ hout,         // [N][128] f32
    u16* __restrict__ h16)            // [N][128] bf16
{
    __shared__ u16 hb0[64 * 128];
    __shared__ u16 hb1[64 * 128];

    const int tid = threadIdx.x;
    const int w = tid >> 6, lane = tid & 63;
    const int l15 = lane & 15, g = lane >> 4;
    const int gbase = blockIdx.x * 64;
    const int j0 = w * 16 + g * 4;

    for (int i = tid; i < 64 * 128 / 2; i += 512) ((u32*)hb0)[i] = 0u;

    bf16x8 Ah[3][4], Ai[3];
#pragma unroll
    for (int a = 0; a < 3; ++a) {
        int gt = w + a * 8;
#pragma unroll
        for (int s = 0; s < 4; ++s)
            Ah[a][s] = *(const bf16x8*)(Ap + ((size_t)(gt * 4 + s) * 64 + lane) * 8);
        Ai[a] = *(const bf16x8*)(Aip + ((size_t)gt * 64 + lane) * 8);
    }

    f32x4 bnh4 = *(const f32x4*)(bhh + 256 + j0);
#pragma unroll
    for (int r = 0; r < 4; ++r) bnh4[r] *= S_N;

    const f32x4 fz = {0.f, 0.f, 0.f, 0.f};
    bf16x8 xdef;
    {
        uint4 u = make_uint4(0u, 0u, 0u, 0u);
        if (g == 2) u.x = 0x3F80u;
        *(uint4*)&xdef = u;
    }

    f32x4 hreg[4];
#pragma unroll
    for (int m = 0; m < 4; ++m) hreg[m] = fz;

    int xoff[4];
#pragma unroll
    for (int m = 0; m < 4; ++m) {
        int nd = gbase + m * 16 + l15;
        nd = nd < NND ? nd : NND - 1;
        xoff[m] = nd * (TT * FI) + g * 8;
    }

    __syncthreads();

    auto dostep = [&](int t, const u16* __restrict__ rb, u16* __restrict__ wb) {
#pragma unroll
        for (int mh = 0; mh < 2; ++mh) {
            const int ma = mh * 2, mb = mh * 2 + 1;
            bf16x8 xf0 = xdef, xf1 = xdef;
            if (g < 2) {
                xf0 = *(const bf16x8*)(xb + (size_t)(xoff[ma] + t * FI));
                xf1 = *(const bf16x8*)(xb + (size_t)(xoff[mb] + t * FI));
            }

            const int ra = ma * 16 + l15, rbr = mb * 16 + l15;
            bf16x8 b0[4], b1[4];
#pragma unroll
            for (int s = 0; s < 4; ++s) {
                b0[s] = *(const bf16x8*)&rb[hidx(ra, s * 32 + g * 8)];
                b1[s] = *(const bf16x8*)&rb[hidx(rbr, s * 32 + g * 8)];
            }

            f32x4 acc[3][2], acci[2];
#pragma unroll
            for (int a = 0; a < 3; ++a) {
                acc[a][0] = __builtin_amdgcn_mfma_f32_16x16x32_bf16(Ah[a][0], b0[0], fz, 0, 0, 0);
                acc[a][1] = __builtin_amdgcn_mfma_f32_16x16x32_bf16(Ah[a][0], b1[0], fz, 0, 0, 0);
            }
#pragma unroll
            for (int s = 1; s < 4; ++s) {
#pragma unroll
                for (int a = 0; a < 3; ++a) {
                    acc[a][0] = __builtin_amdgcn_mfma_f32_16x16x32_bf16(Ah[a][s], b0[s], acc[a][0], 0, 0, 0);
                    acc[a][1] = __builtin_amdgcn_mfma_f32_16x16x32_bf16(Ah[a][s], b1[s], acc[a][1], 0, 0, 0);
                }
            }
            acc[0][0] = __builtin_amdgcn_mfma_f32_16x16x32_bf16(Ai[0], xf0, acc[0][0], 0, 0, 0);
            acc[1][0] = __builtin_amdgcn_mfma_f32_16x16x32_bf16(Ai[1], xf0, acc[1][0], 0, 0, 0);
            acci[0]   = __builtin_amdgcn_mfma_f32_16x16x32_bf16(Ai[2], xf0, fz, 0, 0, 0);
            acc[0][1] = __builtin_amdgcn_mfma_f32_16x16x32_bf16(Ai[0], xf1, acc[0][1], 0, 0, 0);
            acc[1][1] = __builtin_amdgcn_mfma_f32_16x16x32_bf16(Ai[1], xf1, acc[1][1], 0, 0, 0);
            acci[1]   = __builtin_amdgcn_mfma_f32_16x16x32_bf16(Ai[2], xf1, fz, 0, 0, 0);

#pragma unroll
            for (int mi = 0; mi < 2; ++mi) {
                int m = mh * 2 + mi;
#pragma unroll
                for (int r = 0; r < 4; ++r) {
                    float rr = __builtin_amdgcn_rcpf(1.0f + __builtin_amdgcn_exp2f(acc[0][mi][r]));
                    float zz = __builtin_amdgcn_rcpf(1.0f + __builtin_amdgcn_exp2f(acc[1][mi][r]));
                    float na = acci[mi][r] + rr * (acc[2][mi][r] + bnh4[r]);
                    float nn = 2.0f * __builtin_amdgcn_rcpf(1.0f + __builtin_amdgcn_exp2f(na)) - 1.0f;
                    float h = nn + zz * (hreg[m][r] - nn);
                    hreg[m][r] = h;
                }
                u32 p0 = cvtpk(hreg[m][0], hreg[m][1]);
                u32 p1 = cvtpk(hreg[m][2], hreg[m][3]);
                *(uint2*)&wb[hidx(m * 16 + l15, j0)] = make_uint2(p0, p1);
            }
        }
        __syncthreads();
    };

#pragma unroll 1
    for (int tt = 0; tt < TT; tt += 2) {
        dostep(tt, hb0, hb1);
        dostep(tt + 1, hb1, hb0);
    }

#pragma unroll
    for (int m = 0; m < 4; ++m) {
        int nd = gbase + m * 16 + l15;
        if (nd < NND) {
            *(f32x4*)(hout + (size_t)nd * HD + j0) = hreg[m];
            u32 c0 = cvtpk(hreg[m][0], hreg[m][1]);
            u32 c1 = cvtpk(hreg[m][2], hreg[m][3]);
            *(uint2*)(h16 + (size_t)nd * HD + j0) = make_uint2(c0, c1);
        }
    }
}

// ---------------- fused dual projection via MFMA ----------------
// P16[n][0..M) = X@Wl^T (bf16 out); Q[n][0..M) = X@Wr^T + bias (+Xres) (f32 out)
template <int M, bool RES>
__global__ __launch_bounds__(512) void proj2_mfma_kernel(
    const u16* __restrict__ X16,     // [N][128] bf16
    const u16* __restrict__ Wl,      // frags [(M/16)*4*64*8]
    const u16* __restrict__ Wr,
    const float* __restrict__ bias,  // [M]
    const float* __restrict__ Xres,  // [N][128] f32 (RES only)
    u16* __restrict__ P16,           // [N][M] bf16
    float* __restrict__ Q)           // [N][M] f32
{
    __shared__ u16 xs[64 * 128];

    const int tid = threadIdx.x;
    const int w = tid >> 6, lane = tid & 63;
    const int l15 = lane & 15, g = lane >> 4;
    const int gbase = blockIdx.x * 64;
    const f32x4 fz = {0.f, 0.f, 0.f, 0.f};

    // stage X tile (bf16, swizzled)
#pragma unroll
    for (int i = 0; i < 2; ++i) {
        int lin = tid + 512 * i;          // 0..1023
        int n = lin >> 4;                 // 0..63
        int k8 = (lin & 15) * 8;          // octet-aligned
        int gn = gbase + n; if (gn >= NND) gn = NND - 1;
        uint4 v = *(const uint4*)(X16 + (size_t)gn * HD + k8);
        *(uint4*)&xs[hidx(n, k8)] = v;
    }
    __syncthreads();

    if constexpr (M == 128) {
        bf16x8 Al[4], Ar[4];
#pragma unroll
        for (int s = 0; s < 4; ++s) {
            Al[s] = *(const bf16x8*)(Wl + ((size_t)(w * 4 + s) * 64 + lane) * 8);
            Ar[s] = *(const bf16x8*)(Wr + ((size_t)(w * 4 + s) * 64 + lane) * 8);
        }
        const int f0 = w * 16 + g * 4;
        f32x4 bq = *(const f32x4*)(bias + f0);

#pragma unroll
        for (int m = 0; m < 4; ++m) {
            bf16x8 b[4];
#pragma unroll
            for (int s = 0; s < 4; ++s)
                b[s] = *(const bf16x8*)&xs[hidx(m * 16 + l15, s * 32 + g * 8)];
            f32x4 ap = fz, aq = fz;
#pragma unroll
            for (int s = 0; s < 4; ++s) {
                ap = __builtin_amdgcn_mfma_f32_16x16x32_bf16(Al[s], b[s], ap, 0, 0, 0);
                aq = __builtin_amdgcn_mfma_f32_16x16x32_bf16(Ar[s], b[s], aq, 0, 0, 0);
            }
            int nd = gbase + m * 16 + l15;
            if (nd < NND) {
                u32 c0 = cvtpk(ap[0], ap[1]), c1 = cvtpk(ap[2], ap[3]);
                *(uint2*)(P16 + (size_t)nd * M + f0) = make_uint2(c0, c1);
                f32x4 v = aq + bq;
                if constexpr (RES) v += *(const f32x4*)(Xres + (size_t)nd * HD + f0);
                *(f32x4*)(Q + (size_t)nd * M + f0) = v;
            }
        }
    } else {
        // M == 64: waves 0..3 -> P tiles, 4..7 -> Q tiles
        const int tile = w & 3;
        const bool isQ = (w >= 4);
        const u16* Wsel = isQ ? Wr : Wl;
        bf16x8 A[4];
#pragma unroll
        for (int s = 0; s < 4; ++s)
            A[s] = *(const bf16x8*)(Wsel + ((size_t)(tile * 4 + s) * 64 + lane) * 8);
        const int f0 = tile * 16 + g * 4;
        f32x4 bq = *(const f32x4*)(bias + f0);

#pragma unroll
        for (int m = 0; m < 4; ++m) {
            bf16x8 b[4];
#pragma unroll
            for (int s = 0; s < 4; ++s)
                b[s] = *(const bf16x8*)&xs[hidx(m * 16 + l15, s * 32 + g * 8)];
            f32x4 a = fz;
#pragma unroll
            for (int s = 0; s < 4; ++s)
                a = __builtin_amdgcn_mfma_f32_16x16x32_bf16(A[s], b[s], a, 0, 0, 0);
            int nd = gbase + m * 16 + l15;
            if (nd < NND) {
                if (isQ) {
                    f32x4 v = a + bq;
                    *(f32x4*)(Q + (size_t)nd * M + f0) = v;
                } else {
                    u32 c0 = cvtpk(a[0], a[1]), c1 = cvtpk(a[2], a[3]);
                    *(uint2*)(P16 + (size_t)nd * M + f0) = make_uint2(c0, c1);
                }
            }
        }
    }
}

// ---------------- CSR construction ----------------
__global__ void count_kernel(const int* __restrict__ dst, int* __restrict__ cnt) {
    int e = blockIdx.x * 256 + threadIdx.x;
    if (e < NE) atomicAdd(&cnt[dst[e]], 1);
}

__global__ void blocksum_kernel(const int* __restrict__ cnt, int* __restrict__ bsum) {
    __shared__ int sh[256];
    int b = blockIdx.x, t = threadIdx.x;
    int base = b * 1024;
    int s = 0;
    for (int i = t; i < 1024; i += 256) {
        int idx = base + i;
        s += (idx < NND) ? cnt[idx] : 0;
    }
    sh[t] = s; __syncthreads();
    for (int o = 128; o > 0; o >>= 1) { if (t < o) sh[t] += sh[t + o]; __syncthreads(); }
    if (t == 0) bsum[b] = sh[0];
}

__global__ void scanbsum_kernel(int* __restrict__ bsum, int nb, int* __restrict__ rowptr) {
    if (threadIdx.x == 0 && blockIdx.x == 0) {
        int acc = 0;
        for (int i = 0; i < nb; ++i) { int v = bsum[i]; bsum[i] = acc; acc += v; }
        rowptr[NND] = NE;
    }
}

__global__ void scan_kernel(const int* __restrict__ cnt, const int* __restrict__ bsum,
                            int* __restrict__ rowptr) {
    __shared__ int sh[256];
    int b = blockIdx.x, t = threadIdx.x;
    int base = b * 1024;
    int v[4], loc = 0;
#pragma unroll
    for (int j = 0; j < 4; ++j) {
        int idx = base + t * 4 + j;
        v[j] = (idx < NND) ? cnt[idx] : 0;
        loc += v[j];
    }
    sh[t] = loc; __syncthreads();
    for (int o = 1; o < 256; o <<= 1) {
        int x = (t >= o) ? sh[t - o] : 0;
        __syncthreads();
        sh[t] += x;
        __syncthreads();
    }
    int acc = bsum[b] + sh[t] - loc;
#pragma unroll
    for (int j = 0; j < 4; ++j) {
        int idx = base + t * 4 + j;
        if (idx < NND) rowptr[idx] = acc;
        acc += v[j];
    }
}

__global__ void fill_kernel(const int* __restrict__ src, const int* __restrict__ dst,
                            const int* __restrict__ rowptr, int* __restrict__ fill,
                            int* __restrict__ csr) {
    int e = blockIdx.x * 256 + threadIdx.x;
    if (e >= NE) return;
    int d = dst[e];
    int pos = rowptr[d] + atomicAdd(&fill[d], 1);
    csr[pos] = src[e];
}

// ---------------- gathers (bf16 messages) ----------------
__global__ __launch_bounds__(256) void gather1_kernel(
    const u16* __restrict__ P16,     // [N][128] bf16
    const int* __restrict__ rowptr, const int* __restrict__ csr,
    const float* __restrict__ q,     // [N][128] f32
    u16* __restrict__ g16)           // [N][128] bf16 (relu'd)
{
    int n = ((blockIdx.x * 256 + threadIdx.x) >> 6);
    if (n >= NND) return;
    int lane = threadIdx.x & 63;
    int beg = rowptr[n], end = rowptr[n + 1];

    float ax = 0.f, ay = 0.f;
    for (int cb = beg; cb < end; cb += 64) {
        int myi = (cb + lane < end) ? csr[cb + lane] : 0;
        int nn = min(end - cb, 64);
        for (int i = 0; i < nn; ++i) {
            int s = __shfl(myi, i);
            u32 pv = *(const u32*)(P16 + (size_t)s * HD + lane * 2);
            ax += b2f((u16)pv); ay += b2f((u16)(pv >> 16));
        }
    }
    int deg = end - beg;
    float inv = 1.0f / (float)(deg > 0 ? deg : 1);
    float2 qv = *(const float2*)(q + (size_t)n * HD + lane * 2);
    float r0 = fmaxf(ax * inv + qv.x, 0.f);
    float r1 = fmaxf(ay * inv + qv.y, 0.f);
    *(u32*)(g16 + (size_t)n * HD + lane * 2) = cvtpk(r0, r1);
}

__global__ __launch_bounds__(256) void gather2_kernel(
    const u16* __restrict__ P16,     // [N][64] bf16
    const int* __restrict__ rowptr, const int* __restrict__ csr,
    const float* __restrict__ q,     // [N][64] f32
    float* __restrict__ outp)        // [N][64] f32
{
    int n = ((blockIdx.x * 256 + threadIdx.x) >> 6);
    if (n >= NND) return;
    int lane = threadIdx.x & 63;
    int beg = rowptr[n], end = rowptr[n + 1];

    float a = 0.f;
    for (int cb = beg; cb < end; cb += 64) {
        int myi = (cb + lane < end) ? csr[cb + lane] : 0;
        int nn = min(end - cb, 64);
        for (int i = 0; i < nn; ++i) {
            int s = __shfl(myi, i);
            a += b2f(P16[(size_t)s * OD + lane]);
        }
    }
    int deg = end - beg;
    float inv = 1.0f / (float)(deg > 0 ? deg : 1);
    outp[(size_t)n * OD + lane] = a * inv + q[(size_t)n * OD + lane];
}

// ---------------- launch ----------------
extern "C" void kernel_launch(void* const* d_in, const int* in_sizes, int n_in,
                              void* d_out, int out_size, void* d_ws, size_t ws_size,
                              hipStream_t stream) {
    const float* x   = (const float*)d_in[0];
    const int*   edg = (const int*)d_in[1];
    const int*   src = edg;
    const int*   dst = edg + NE;
    const float* Wih = (const float*)d_in[2];
    const float* Whh = (const float*)d_in[3];
    const float* bih = (const float*)d_in[4];
    const float* bhh = (const float*)d_in[5];
    const float* W1l = (const float*)d_in[6];
    const float* b1  = (const float*)d_in[7];
    const float* W1r = (const float*)d_in[8];
    const float* W2l = (const float*)d_in[9];
    const float* b2  = (const float*)d_in[10];
    const float* W2r = (const float*)d_in[11];
    float* out = (float*)d_out;

    char* wsp = (char*)d_ws;
    auto alloc = [&](size_t nbytes) {
        char* p = wsp; wsp += (nbytes + 255) & ~(size_t)255; return p;
    };
    u16*   Ap    = (u16*)alloc((size_t)6144 * 8 * 2);
    u16*   Aip   = (u16*)alloc((size_t)1536 * 8 * 2);
    u16*   Pw1l  = (u16*)alloc((size_t)2048 * 8 * 2);   // 128 rows -> 2048 frag-slots
    u16*   Pw1r  = (u16*)alloc((size_t)2048 * 8 * 2);
    u16*   Pw2l  = (u16*)alloc((size_t)1024 * 8 * 2);   // 64 rows
    u16*   Pw2r  = (u16*)alloc((size_t)1024 * 8 * 2);
    int*   cnt   = (int*)alloc((size_t)NND * 4);
    int*   fill  = (int*)alloc((size_t)NND * 4);
    int*   rowp  = (int*)alloc((size_t)(NND + 1) * 4);
    int*   bsum  = (int*)alloc((size_t)128 * 4);
    int*   csr   = (int*)alloc((size_t)NE * 4);
    float* h     = (float*)alloc((size_t)NND * HD * 4);   // f32 (residual)
    u16*   h16   = (u16*)alloc((size_t)NND * HD * 2);
    float* q     = (float*)alloc((size_t)NND * HD * 4);   // layer1 Q f32; reused as q2
    u16*   P16   = (u16*)alloc((size_t)NND * HD * 2);     // layer1 P bf16; reused as P2
    u16*   g16   = (u16*)alloc((size_t)NND * HD * 2);
    // xb ([N][T][16] bf16 = 76.8 MB) aliases q (51.2) + P16 (25.6) = 76.8 MB:
    // consumed by the GRU before q/P16 are first written (same stream -> ordered).
    u16*   xb    = (u16*)q;
    float* q2    = q;            // layer2 Q f32 [N][64] (q consumed by gather1 first)
    u16*   P16b  = P16;          // layer2 P bf16 [N][64]

    const int NB_SCAN = (NND + 1023) / 1024;

    hipMemsetAsync(cnt, 0, (size_t)NND * 4, stream);
    hipMemsetAsync(fill, 0, (size_t)NND * 4, stream);

    // prep
    cvt_x_kernel<<<(NND * TT * FI) / (256 * 8), 256, 0, stream>>>(x, xb);
    pack_w_kernel<<<30, 256, 0, stream>>>(Whh, Wih, bih, bhh, Ap, Aip);
    pack_gemm_kernel<<<8, 256, 0, stream>>>(W1l, Pw1l, HD);
    pack_gemm_kernel<<<8, 256, 0, stream>>>(W1r, Pw1r, HD);
    pack_gemm_kernel<<<4, 256, 0, stream>>>(W2l, Pw2l, OD);
    pack_gemm_kernel<<<4, 256, 0, stream>>>(W2r, Pw2r, OD);

    // CSR build
    count_kernel<<<(NE + 255) / 256, 256, 0, stream>>>(dst, cnt);
    blocksum_kernel<<<NB_SCAN, 256, 0, stream>>>(cnt, bsum);
    scanbsum_kernel<<<1, 64, 0, stream>>>(bsum, NB_SCAN, rowp);
    scan_kernel<<<NB_SCAN, 256, 0, stream>>>(cnt, bsum, rowp);
    fill_kernel<<<(NE + 255) / 256, 256, 0, stream>>>(src, dst, rowp, fill, csr);

    // GRU -> h (f32) + h16 (bf16)
    const int nblk = (NND + 63) / 64;
    gru_mfma_kernel<<<nblk, 512, 0, stream>>>(xb, Ap, Aip, bhh, h, h16);

    // layer 1: fused dual MFMA projection, then mean-gather (+q, relu) -> g16
    proj2_mfma_kernel<HD, true><<<nblk, 512, 0, stream>>>(h16, Pw1l, Pw1r, b1, h, P16, q);
    gather1_kernel<<<(NND * 64 + 255) / 256, 256, 0, stream>>>(P16, rowp, csr, q, g16);

    // layer 2: fused dual MFMA projection to 64, then mean-gather (+q2) -> out
    proj2_mfma_kernel<OD, false><<<nblk, 512, 0, stream>>>(g16, Pw2l, Pw2r, b2, nullptr, P16b, q2);
    gather2_kernel<<<(NND * 64 + 255) / 256, 256, 0, stream>>>(P16b, rowp, csr, q2, out);
}

// Round 9
// 831.888 us; speedup vs baseline: 1.7323x; 1.0221x over previous
//
#include <hip/hip_runtime.h>
#include <math.h>

#define NND 100000
#define TT 24
#define FI 16
#define HD 128
#define GD 384   // 3*HD
#define OD 64
#define NE 1600000

typedef __bf16 bf16x8 __attribute__((ext_vector_type(8)));
typedef float f32x4 __attribute__((ext_vector_type(4)));
typedef unsigned short u16;
typedef unsigned int u32;

#define S_RZ (-1.44269504f)   // -log2(e): sigmoid via rcp(1+exp2(s*a))
#define S_N  (-2.88539008f)   // -2*log2(e): tanh via 2*rcp(1+exp2(s*a))-1

__device__ __forceinline__ u16 f2b(float f) {
    u32 u = __float_as_uint(f);
    u32 r = (u + 0x7FFFu + ((u >> 16) & 1u)) >> 16;
    return (u16)r;
}
__device__ __forceinline__ u32 cvtpk(float lo, float hi) {
    u32 r;
    asm("v_cvt_pk_bf16_f32 %0, %1, %2" : "=v"(r) : "v"(lo), "v"(hi));
    return r;
}
__device__ __forceinline__ float b2f(u16 v) {
    return __uint_as_float((u32)v << 16);
}

// ---------------- x f32 -> bf16 (once) ----------------
__global__ void cvt_x_kernel(const float* __restrict__ x, u16* __restrict__ xb) {
    size_t base = ((size_t)blockIdx.x * 256 + threadIdx.x) * 8;
    float4 a = *(const float4*)(x + base);
    float4 b = *(const float4*)(x + base + 4);
    u32 o0 = cvtpk(a.x, a.y), o1 = cvtpk(a.z, a.w);
    u32 o2 = cvtpk(b.x, b.y), o3 = cvtpk(b.z, b.w);
    *(uint4*)(xb + base) = make_uint4(o0, o1, o2, o3);
}

// ---------------- pack GRU weights into MFMA A-fragments (bf16, scale-folded) ----------------
__global__ void pack_w_kernel(const float* __restrict__ Whh, const float* __restrict__ Wih,
                              const float* __restrict__ bih, const float* __restrict__ bhh,
                              u16* __restrict__ Ap, u16* __restrict__ Aip) {
    int id = blockIdx.x * 256 + threadIdx.x;
    if (id < 6144) {
        int lane = id & 63, fs = id >> 6;
        int s = fs & 3, gt = fs >> 2;
        int row = gt * 16 + (lane & 15);
        float sc = (row < 2 * HD) ? S_RZ : S_N;
        int k0 = s * 32 + (lane >> 4) * 8;
        const float* src = Whh + (size_t)row * HD + k0;
        u16 o[8];
#pragma unroll
        for (int e = 0; e < 8; ++e) o[e] = f2b(src[e] * sc);
        u32* dst = (u32*)(Ap + (size_t)id * 8);
#pragma unroll
        for (int e = 0; e < 4; ++e) dst[e] = (u32)o[2 * e] | ((u32)o[2 * e + 1] << 16);
    } else if (id < 7680) {
        int id2 = id - 6144;
        int lane = id2 & 63, gt = id2 >> 6;
        int row = gt * 16 + (lane & 15);
        float sc = (row < 2 * HD) ? S_RZ : S_N;
        int g = lane >> 4;
        u16 o[8] = {0, 0, 0, 0, 0, 0, 0, 0};
        if (g < 2) {
            const float* src = Wih + (size_t)row * FI + g * 8;
#pragma unroll
            for (int e = 0; e < 8; ++e) o[e] = f2b(src[e] * sc);
        } else if (g == 2) {
            float bias = (row < 2 * HD) ? (bih[row] + bhh[row]) : bih[row];
            o[0] = f2b(bias * sc);
        }
        u32* dst = (u32*)(Aip + (size_t)id2 * 8);
#pragma unroll
        for (int e = 0; e < 4; ++e) dst[e] = (u32)o[2 * e] | ((u32)o[2 * e + 1] << 16);
    }
}

// ---------------- pack GEMM weight W[rows][128] into A-frags ----------------
__global__ void pack_gemm_kernel(const float* __restrict__ W, u16* __restrict__ F, int rows) {
    int id = blockIdx.x * 256 + threadIdx.x;
    if (id >= rows * 16) return;
    int lane = id & 63, fs = id >> 6;
    int s = fs & 3, tile = fs >> 2;
    int row = tile * 16 + (lane & 15);
    int k0 = s * 32 + (lane >> 4) * 8;
    const float* src = W + (size_t)row * HD + k0;
    u16 o[8];
#pragma unroll
    for (int e = 0; e < 8; ++e) o[e] = f2b(src[e]);
    u32* dst = (u32*)(F + (size_t)id * 8);
#pragma unroll
    for (int e = 0; e < 4; ++e) dst[e] = (u32)o[2 * e] | ((u32)o[2 * e + 1] << 16);
}

// swizzled LDS index (u16 units): row stride 128, XOR bank swizzle
__device__ __forceinline__ int hidx(int row, int col) {
    return row * 128 + (col ^ ((row & 7) << 3));
}

// ---------------- GRU via MFMA + fused layer-1 dual projection epilogue ----------------
__global__ __launch_bounds__(512) void gru_mfma_kernel(
    const u16* __restrict__ xb,       // [N][T][16] bf16
    const u16* __restrict__ Ap,       // GRU Whh frags (scaled)
    const u16* __restrict__ Aip,      // GRU Wih' frags (scaled, bias k=16)
    const float* __restrict__ bhh,
    const u16* __restrict__ Wl,       // W1l frags
    const u16* __restrict__ Wr,       // W1r frags
    const float* __restrict__ b1,
    u16* __restrict__ P16,            // [N][128] bf16  = h@W1l^T
    float* __restrict__ q)            // [N][128] f32   = h@W1r^T + b1 + h
{
    __shared__ u16 hb0[64 * 128];
    __shared__ u16 hb1[64 * 128];

    const int tid = threadIdx.x;
    const int w = tid >> 6, lane = tid & 63;
    const int l15 = lane & 15, g = lane >> 4;
    const int gbase = blockIdx.x * 64;
    const int j0 = w * 16 + g * 4;

    for (int i = tid; i < 64 * 128 / 2; i += 512) ((u32*)hb0)[i] = 0u;

    bf16x8 Ah[3][4], Ai[3];
#pragma unroll
    for (int a = 0; a < 3; ++a) {
        int gt = w + a * 8;
#pragma unroll
        for (int s = 0; s < 4; ++s)
            Ah[a][s] = *(const bf16x8*)(Ap + ((size_t)(gt * 4 + s) * 64 + lane) * 8);
        Ai[a] = *(const bf16x8*)(Aip + ((size_t)gt * 64 + lane) * 8);
    }

    f32x4 bnh4 = *(const f32x4*)(bhh + 256 + j0);
#pragma unroll
    for (int r = 0; r < 4; ++r) bnh4[r] *= S_N;

    const f32x4 fz = {0.f, 0.f, 0.f, 0.f};
    bf16x8 xdef;
    {
        uint4 u = make_uint4(0u, 0u, 0u, 0u);
        if (g == 2) u.x = 0x3F80u;
        *(uint4*)&xdef = u;
    }

    f32x4 hreg[4];
#pragma unroll
    for (int m = 0; m < 4; ++m) hreg[m] = fz;

    int xoff[4];
#pragma unroll
    for (int m = 0; m < 4; ++m) {
        int nd = gbase + m * 16 + l15;
        nd = nd < NND ? nd : NND - 1;
        xoff[m] = nd * (TT * FI) + g * 8;
    }

    __syncthreads();

    auto dostep = [&](int t, const u16* __restrict__ rb, u16* __restrict__ wb) {
#pragma unroll
        for (int mh = 0; mh < 2; ++mh) {
            const int ma = mh * 2, mb = mh * 2 + 1;
            bf16x8 xf0 = xdef, xf1 = xdef;
            if (g < 2) {
                xf0 = *(const bf16x8*)(xb + (size_t)(xoff[ma] + t * FI));
                xf1 = *(const bf16x8*)(xb + (size_t)(xoff[mb] + t * FI));
            }

            const int ra = ma * 16 + l15, rbr = mb * 16 + l15;
            bf16x8 b0[4], b1f[4];
#pragma unroll
            for (int s = 0; s < 4; ++s) {
                b0[s]  = *(const bf16x8*)&rb[hidx(ra, s * 32 + g * 8)];
                b1f[s] = *(const bf16x8*)&rb[hidx(rbr, s * 32 + g * 8)];
            }

            f32x4 acc[3][2], acci[2];
#pragma unroll
            for (int a = 0; a < 3; ++a) {
                acc[a][0] = __builtin_amdgcn_mfma_f32_16x16x32_bf16(Ah[a][0], b0[0], fz, 0, 0, 0);
                acc[a][1] = __builtin_amdgcn_mfma_f32_16x16x32_bf16(Ah[a][0], b1f[0], fz, 0, 0, 0);
            }
#pragma unroll
            for (int s = 1; s < 4; ++s) {
#pragma unroll
                for (int a = 0; a < 3; ++a) {
                    acc[a][0] = __builtin_amdgcn_mfma_f32_16x16x32_bf16(Ah[a][s], b0[s], acc[a][0], 0, 0, 0);
                    acc[a][1] = __builtin_amdgcn_mfma_f32_16x16x32_bf16(Ah[a][s], b1f[s], acc[a][1], 0, 0, 0);
                }
            }
            acc[0][0] = __builtin_amdgcn_mfma_f32_16x16x32_bf16(Ai[0], xf0, acc[0][0], 0, 0, 0);
            acc[1][0] = __builtin_amdgcn_mfma_f32_16x16x32_bf16(Ai[1], xf0, acc[1][0], 0, 0, 0);
            acci[0]   = __builtin_amdgcn_mfma_f32_16x16x32_bf16(Ai[2], xf0, fz, 0, 0, 0);
            acc[0][1] = __builtin_amdgcn_mfma_f32_16x16x32_bf16(Ai[0], xf1, acc[0][1], 0, 0, 0);
            acc[1][1] = __builtin_amdgcn_mfma_f32_16x16x32_bf16(Ai[1], xf1, acc[1][1], 0, 0, 0);
            acci[1]   = __builtin_amdgcn_mfma_f32_16x16x32_bf16(Ai[2], xf1, fz, 0, 0, 0);

#pragma unroll
            for (int mi = 0; mi < 2; ++mi) {
                int m = mh * 2 + mi;
#pragma unroll
                for (int r = 0; r < 4; ++r) {
                    float rr = __builtin_amdgcn_rcpf(1.0f + __builtin_amdgcn_exp2f(acc[0][mi][r]));
                    float zz = __builtin_amdgcn_rcpf(1.0f + __builtin_amdgcn_exp2f(acc[1][mi][r]));
                    float na = acci[mi][r] + rr * (acc[2][mi][r] + bnh4[r]);
                    float nn = 2.0f * __builtin_amdgcn_rcpf(1.0f + __builtin_amdgcn_exp2f(na)) - 1.0f;
                    float h = nn + zz * (hreg[m][r] - nn);
                    hreg[m][r] = h;
                }
                u32 p0 = cvtpk(hreg[m][0], hreg[m][1]);
                u32 p1 = cvtpk(hreg[m][2], hreg[m][3]);
                *(uint2*)&wb[hidx(m * 16 + l15, j0)] = make_uint2(p0, p1);
            }
        }
        __syncthreads();
    };

#pragma unroll 1
    for (int tt = 0; tt < TT; tt += 2) {
        dostep(tt, hb0, hb1);
        dostep(tt + 1, hb1, hb0);
    }
    // final h (bf16, swizzled) now lives in hb0; f32 copy in hreg.

    // ---- fused layer-1 dual projection ----
    bf16x8 Al[4], Ar[4];
#pragma unroll
    for (int s = 0; s < 4; ++s) {
        Al[s] = *(const bf16x8*)(Wl + ((size_t)(w * 4 + s) * 64 + lane) * 8);
        Ar[s] = *(const bf16x8*)(Wr + ((size_t)(w * 4 + s) * 64 + lane) * 8);
    }
    f32x4 bq = *(const f32x4*)(b1 + j0);   // output f-range == j0 range

#pragma unroll
    for (int m = 0; m < 4; ++m) {
        bf16x8 b[4];
#pragma unroll
        for (int s = 0; s < 4; ++s)
            b[s] = *(const bf16x8*)&hb0[hidx(m * 16 + l15, s * 32 + g * 8)];
        f32x4 ap = fz, aq = fz;
#pragma unroll
        for (int s = 0; s < 4; ++s) {
            ap = __builtin_amdgcn_mfma_f32_16x16x32_bf16(Al[s], b[s], ap, 0, 0, 0);
            aq = __builtin_amdgcn_mfma_f32_16x16x32_bf16(Ar[s], b[s], aq, 0, 0, 0);
        }
        int nd = gbase + m * 16 + l15;
        if (nd < NND) {
            u32 c0 = cvtpk(ap[0], ap[1]), c1 = cvtpk(ap[2], ap[3]);
            *(uint2*)(P16 + (size_t)nd * HD + j0) = make_uint2(c0, c1);
            f32x4 v = aq + bq + hreg[m];   // residual from f32 registers
            *(f32x4*)(q + (size_t)nd * HD + j0) = v;
        }
    }
}

// ---------------- CSR construction ----------------
__global__ void count_kernel(const int* __restrict__ dst, int* __restrict__ cnt) {
    int e = blockIdx.x * 256 + threadIdx.x;
    if (e < NE) atomicAdd(&cnt[dst[e]], 1);
}

__global__ void blocksum_kernel(const int* __restrict__ cnt, int* __restrict__ bsum) {
    __shared__ int sh[256];
    int b = blockIdx.x, t = threadIdx.x;
    int base = b * 1024;
    int s = 0;
    for (int i = t; i < 1024; i += 256) {
        int idx = base + i;
        s += (idx < NND) ? cnt[idx] : 0;
    }
    sh[t] = s; __syncthreads();
    for (int o = 128; o > 0; o >>= 1) { if (t < o) sh[t] += sh[t + o]; __syncthreads(); }
    if (t == 0) bsum[b] = sh[0];
}

__global__ void scanbsum_kernel(int* __restrict__ bsum, int nb, int* __restrict__ rowptr) {
    if (threadIdx.x == 0 && blockIdx.x == 0) {
        int acc = 0;
        for (int i = 0; i < nb; ++i) { int v = bsum[i]; bsum[i] = acc; acc += v; }
        rowptr[NND] = NE;
    }
}

__global__ void scan_kernel(const int* __restrict__ cnt, const int* __restrict__ bsum,
                            int* __restrict__ rowptr) {
    __shared__ int sh[256];
    int b = blockIdx.x, t = threadIdx.x;
    int base = b * 1024;
    int v[4], loc = 0;
#pragma unroll
    for (int j = 0; j < 4; ++j) {
        int idx = base + t * 4 + j;
        v[j] = (idx < NND) ? cnt[idx] : 0;
        loc += v[j];
    }
    sh[t] = loc; __syncthreads();
    for (int o = 1; o < 256; o <<= 1) {
        int x = (t >= o) ? sh[t - o] : 0;
        __syncthreads();
        sh[t] += x;
        __syncthreads();
    }
    int acc = bsum[b] + sh[t] - loc;
#pragma unroll
    for (int j = 0; j < 4; ++j) {
        int idx = base + t * 4 + j;
        if (idx < NND) rowptr[idx] = acc;
        acc += v[j];
    }
}

__global__ void fill_kernel(const int* __restrict__ src, const int* __restrict__ dst,
                            const int* __restrict__ rowptr, int* __restrict__ fill,
                            int* __restrict__ csr) {
    int e = blockIdx.x * 256 + threadIdx.x;
    if (e >= NE) return;
    int d = dst[e];
    int pos = rowptr[d] + atomicAdd(&fill[d], 1);
    csr[pos] = src[e];
}

// ---------------- fused gather (layer1 mean+relu) + layer-2 dual projection ----------------
__global__ __launch_bounds__(512) void gather_proj_kernel(
    const u16* __restrict__ P16,     // [N][128] bf16 messages
    const int* __restrict__ rowptr, const int* __restrict__ csr,
    const float* __restrict__ q,     // [N][128] f32 self-path
    const u16* __restrict__ W2l, const u16* __restrict__ W2r,   // frags
    const float* __restrict__ b2,
    u16* __restrict__ P2,            // [N][64] bf16
    float* __restrict__ q2)          // [N][64] f32
{
    __shared__ u16 xs[64 * 128];

    const int tid = threadIdx.x;
    const int w = tid >> 6, lane = tid & 63;
    const int l15 = lane & 15, g = lane >> 4;
    const int gbase = blockIdx.x * 64;
    const f32x4 fz = {0.f, 0.f, 0.f, 0.f};

    // phase 1: each wave gathers 8 nodes -> relu'd g rows into swizzled LDS
#pragma unroll 1
    for (int i = 0; i < 8; ++i) {
        int nloc = w * 8 + i;
        int n = gbase + nloc;
        u32 gv = 0u;
        if (n < NND) {
            int beg = rowptr[n], end = rowptr[n + 1];
            float ax = 0.f, ay = 0.f;
            for (int cb = beg; cb < end; cb += 64) {
                int myi = (cb + lane < end) ? csr[cb + lane] : 0;
                int nn = min(end - cb, 64);
                for (int ii = 0; ii < nn; ++ii) {
                    int s = __shfl(myi, ii);
                    u32 pv = *(const u32*)(P16 + (size_t)s * HD + lane * 2);
                    ax += b2f((u16)pv); ay += b2f((u16)(pv >> 16));
                }
            }
            int deg = end - beg;
            float inv = 1.0f / (float)(deg > 0 ? deg : 1);
            float2 qv = *(const float2*)(q + (size_t)n * HD + lane * 2);
            gv = cvtpk(fmaxf(ax * inv + qv.x, 0.f), fmaxf(ay * inv + qv.y, 0.f));
        }
        *(u32*)&xs[hidx(nloc, lane * 2)] = gv;
    }
    __syncthreads();

    // phase 2: M=64 dual projection (waves 0-3 -> P2 tiles, 4-7 -> Q2 tiles)
    const int tile = w & 3;
    const bool isQ = (w >= 4);
    const u16* Wsel = isQ ? W2r : W2l;
    bf16x8 A[4];
#pragma unroll
    for (int s = 0; s < 4; ++s)
        A[s] = *(const bf16x8*)(Wsel + ((size_t)(tile * 4 + s) * 64 + lane) * 8);
    const int f0 = tile * 16 + g * 4;
    f32x4 bq = *(const f32x4*)(b2 + f0);

#pragma unroll
    for (int m = 0; m < 4; ++m) {
        bf16x8 b[4];
#pragma unroll
        for (int s = 0; s < 4; ++s)
            b[s] = *(const bf16x8*)&xs[hidx(m * 16 + l15, s * 32 + g * 8)];
        f32x4 a = fz;
#pragma unroll
        for (int s = 0; s < 4; ++s)
            a = __builtin_amdgcn_mfma_f32_16x16x32_bf16(A[s], b[s], a, 0, 0, 0);
        int nd = gbase + m * 16 + l15;
        if (nd < NND) {
            if (isQ) {
                f32x4 v = a + bq;
                *(f32x4*)(q2 + (size_t)nd * OD + f0) = v;
            } else {
                u32 c0 = cvtpk(a[0], a[1]), c1 = cvtpk(a[2], a[3]);
                *(uint2*)(P2 + (size_t)nd * OD + f0) = make_uint2(c0, c1);
            }
        }
    }
}

// ---------------- final gather (layer2 mean) ----------------
__global__ __launch_bounds__(256) void gather2_kernel(
    const u16* __restrict__ P2,      // [N][64] bf16
    const int* __restrict__ rowptr, const int* __restrict__ csr,
    const float* __restrict__ q2,    // [N][64] f32
    float* __restrict__ outp)        // [N][64] f32
{
    int n = ((blockIdx.x * 256 + threadIdx.x) >> 6);
    if (n >= NND) return;
    int lane = threadIdx.x & 63;
    int beg = rowptr[n], end = rowptr[n + 1];

    float a = 0.f;
    for (int cb = beg; cb < end; cb += 64) {
        int myi = (cb + lane < end) ? csr[cb + lane] : 0;
        int nn = min(end - cb, 64);
        for (int i = 0; i < nn; ++i) {
            int s = __shfl(myi, i);
            a += b2f(P2[(size_t)s * OD + lane]);
        }
    }
    int deg = end - beg;
    float inv = 1.0f / (float)(deg > 0 ? deg : 1);
    outp[(size_t)n * OD + lane] = a * inv + q2[(size_t)n * OD + lane];
}

// ---------------- launch ----------------
extern "C" void kernel_launch(void* const* d_in, const int* in_sizes, int n_in,
                              void* d_out, int out_size, void* d_ws, size_t ws_size,
                              hipStream_t stream) {
    const float* x   = (const float*)d_in[0];
    const int*   edg = (const int*)d_in[1];
    const int*   src = edg;
    const int*   dst = edg + NE;
    const float* Wih = (const float*)d_in[2];
    const float* Whh = (const float*)d_in[3];
    const float* bih = (const float*)d_in[4];
    const float* bhh = (const float*)d_in[5];
    const float* W1l = (const float*)d_in[6];
    const float* b1  = (const float*)d_in[7];
    const float* W1r = (const float*)d_in[8];
    const float* W2l = (const float*)d_in[9];
    const float* b2  = (const float*)d_in[10];
    const float* W2r = (const float*)d_in[11];
    float* out = (float*)d_out;

    char* wsp = (char*)d_ws;
    auto alloc = [&](size_t nbytes) {
        char* p = wsp; wsp += (nbytes + 255) & ~(size_t)255; return p;
    };
    u16*   Ap    = (u16*)alloc((size_t)6144 * 8 * 2);
    u16*   Aip   = (u16*)alloc((size_t)1536 * 8 * 2);
    u16*   Pw1l  = (u16*)alloc((size_t)2048 * 8 * 2);
    u16*   Pw1r  = (u16*)alloc((size_t)2048 * 8 * 2);
    u16*   Pw2l  = (u16*)alloc((size_t)1024 * 8 * 2);
    u16*   Pw2r  = (u16*)alloc((size_t)1024 * 8 * 2);
    int*   cnt   = (int*)alloc((size_t)NND * 4);
    int*   fill  = (int*)alloc((size_t)NND * 4);
    int*   rowp  = (int*)alloc((size_t)(NND + 1) * 4);
    int*   bsum  = (int*)alloc((size_t)128 * 4);
    int*   csr   = (int*)alloc((size_t)NE * 4);
    u16*   xb    = (u16*)alloc((size_t)NND * TT * FI * 2);   // 76.8 MB, no aliasing
    float* q     = (float*)alloc((size_t)NND * HD * 4);      // 51.2 MB
    u16*   P16   = (u16*)alloc((size_t)NND * HD * 2);        // 25.6 MB
    u16*   P2    = (u16*)alloc((size_t)NND * OD * 2);        // 12.8 MB
    float* q2    = (float*)alloc((size_t)NND * OD * 4);      // 25.6 MB

    const int NB_SCAN = (NND + 1023) / 1024;

    hipMemsetAsync(cnt, 0, (size_t)NND * 4, stream);
    hipMemsetAsync(fill, 0, (size_t)NND * 4, stream);

    // prep
    cvt_x_kernel<<<(NND * TT * FI) / (256 * 8), 256, 0, stream>>>(x, xb);
    pack_w_kernel<<<30, 256, 0, stream>>>(Whh, Wih, bih, bhh, Ap, Aip);
    pack_gemm_kernel<<<8, 256, 0, stream>>>(W1l, Pw1l, HD);
    pack_gemm_kernel<<<8, 256, 0, stream>>>(W1r, Pw1r, HD);
    pack_gemm_kernel<<<4, 256, 0, stream>>>(W2l, Pw2l, OD);
    pack_gemm_kernel<<<4, 256, 0, stream>>>(W2r, Pw2r, OD);

    // CSR build
    count_kernel<<<(NE + 255) / 256, 256, 0, stream>>>(dst, cnt);
    blocksum_kernel<<<NB_SCAN, 256, 0, stream>>>(cnt, bsum);
    scanbsum_kernel<<<1, 64, 0, stream>>>(bsum, NB_SCAN, rowp);
    scan_kernel<<<NB_SCAN, 256, 0, stream>>>(cnt, bsum, rowp);
    fill_kernel<<<(NE + 255) / 256, 256, 0, stream>>>(src, dst, rowp, fill, csr);

    // GRU + fused layer-1 projection -> P16 (bf16), q (f32, bias+residual)
    const int nblk = (NND + 63) / 64;
    gru_mfma_kernel<<<nblk, 512, 0, stream>>>(xb, Ap, Aip, bhh, Pw1l, Pw1r, b1, P16, q);

    // gather layer-1 (+relu) fused with layer-2 projection -> P2, q2
    gather_proj_kernel<<<nblk, 512, 0, stream>>>(P16, rowp, csr, q, Pw2l, Pw2r, b2, P2, q2);

    // final mean-gather -> out
    gather2_kernel<<<(NND * 64 + 255) / 256, 256, 0, stream>>>(P2, rowp, csr, q2, out);
}

// Round 10
// 733.140 us; speedup vs baseline: 1.9657x; 1.1347x over previous
//
#include <hip/hip_runtime.h>
#include <math.h>

#define NND 100000
#define TT 24
#define FI 16
#define HD 128
#define GD 384   // 3*HD
#define OD 64
#define NE 1600000

typedef __bf16 bf16x8 __attribute__((ext_vector_type(8)));
typedef float f32x4 __attribute__((ext_vector_type(4)));
typedef unsigned short u16;
typedef unsigned int u32;

#define S_RZ (-1.44269504f)   // -log2(e): sigmoid via rcp(1+exp2(s*a))
#define S_N  (-2.88539008f)   // -2*log2(e): tanh via 2*rcp(1+exp2(s*a))-1

__device__ __forceinline__ u16 f2b(float f) {
    u32 u = __float_as_uint(f);
    u32 r = (u + 0x7FFFu + ((u >> 16) & 1u)) >> 16;
    return (u16)r;
}
__device__ __forceinline__ u32 cvtpk(float lo, float hi) {
    u32 r;
    asm("v_cvt_pk_bf16_f32 %0, %1, %2" : "=v"(r) : "v"(lo), "v"(hi));
    return r;
}
__device__ __forceinline__ float b2f(u16 v) {
    return __uint_as_float((u32)v << 16);
}

// ---------------- x f32 -> bf16 (once) ----------------
__global__ void cvt_x_kernel(const float* __restrict__ x, u16* __restrict__ xb) {
    size_t base = ((size_t)blockIdx.x * 256 + threadIdx.x) * 8;
    float4 a = *(const float4*)(x + base);
    float4 b = *(const float4*)(x + base + 4);
    u32 o0 = cvtpk(a.x, a.y), o1 = cvtpk(a.z, a.w);
    u32 o2 = cvtpk(b.x, b.y), o3 = cvtpk(b.z, b.w);
    *(uint4*)(xb + base) = make_uint4(o0, o1, o2, o3);
}

// ---------------- pack GRU weights into MFMA A-fragments (bf16, scale-folded) ----------------
__global__ void pack_w_kernel(const float* __restrict__ Whh, const float* __restrict__ Wih,
                              const float* __restrict__ bih, const float* __restrict__ bhh,
                              u16* __restrict__ Ap, u16* __restrict__ Aip) {
    int id = blockIdx.x * 256 + threadIdx.x;
    if (id < 6144) {
        int lane = id & 63, fs = id >> 6;
        int s = fs & 3, gt = fs >> 2;
        int row = gt * 16 + (lane & 15);
        float sc = (row < 2 * HD) ? S_RZ : S_N;
        int k0 = s * 32 + (lane >> 4) * 8;
        const float* src = Whh + (size_t)row * HD + k0;
        u16 o[8];
#pragma unroll
        for (int e = 0; e < 8; ++e) o[e] = f2b(src[e] * sc);
        u32* dst = (u32*)(Ap + (size_t)id * 8);
#pragma unroll
        for (int e = 0; e < 4; ++e) dst[e] = (u32)o[2 * e] | ((u32)o[2 * e + 1] << 16);
    } else if (id < 7680) {
        int id2 = id - 6144;
        int lane = id2 & 63, gt = id2 >> 6;
        int row = gt * 16 + (lane & 15);
        float sc = (row < 2 * HD) ? S_RZ : S_N;
        int g = lane >> 4;
        u16 o[8] = {0, 0, 0, 0, 0, 0, 0, 0};
        if (g < 2) {
            const float* src = Wih + (size_t)row * FI + g * 8;
#pragma unroll
            for (int e = 0; e < 8; ++e) o[e] = f2b(src[e] * sc);
        } else if (g == 2) {
            float bias = (row < 2 * HD) ? (bih[row] + bhh[row]) : bih[row];
            o[0] = f2b(bias * sc);
        }
        u32* dst = (u32*)(Aip + (size_t)id2 * 8);
#pragma unroll
        for (int e = 0; e < 4; ++e) dst[e] = (u32)o[2 * e] | ((u32)o[2 * e + 1] << 16);
    }
}

// ---------------- pack GEMM weight W[rows][128] into A-frags ----------------
__global__ void pack_gemm_kernel(const float* __restrict__ W, u16* __restrict__ F, int rows) {
    int id = blockIdx.x * 256 + threadIdx.x;
    if (id >= rows * 16) return;
    int lane = id & 63, fs = id >> 6;
    int s = fs & 3, tile = fs >> 2;
    int row = tile * 16 + (lane & 15);
    int k0 = s * 32 + (lane >> 4) * 8;
    const float* src = W + (size_t)row * HD + k0;
    u16 o[8];
#pragma unroll
    for (int e = 0; e < 8; ++e) o[e] = f2b(src[e]);
    u32* dst = (u32*)(F + (size_t)id * 8);
#pragma unroll
    for (int e = 0; e < 4; ++e) dst[e] = (u32)o[2 * e] | ((u32)o[2 * e + 1] << 16);
}

// swizzled LDS index (u16 units): row stride 128, XOR bank swizzle
__device__ __forceinline__ int hidx(int row, int col) {
    return row * 128 + (col ^ ((row & 7) << 3));
}

// ---------------- GRU via MFMA + fused layer-1 dual projection epilogue ----------------
// __launch_bounds__(512, 1): raise the register budget so the 15 weight
// fragments (120 VGPRs) stay register-resident across all 24 steps instead of
// being rematerialized from L2 every step (~11.5 GB of L2 traffic at VGPR=84).
__global__ __launch_bounds__(512, 1) void gru_mfma_kernel(
    const u16* __restrict__ xb,       // [N][T][16] bf16
    const u16* __restrict__ Ap,       // GRU Whh frags (scaled)
    const u16* __restrict__ Aip,      // GRU Wih' frags (scaled, bias k=16)
    const float* __restrict__ bhh,
    const u16* __restrict__ Wl,       // W1l frags
    const u16* __restrict__ Wr,       // W1r frags
    const float* __restrict__ b1,
    u16* __restrict__ P16,            // [N][128] bf16  = h@W1l^T
    float* __restrict__ q)            // [N][128] f32   = h@W1r^T + b1 + h
{
    __shared__ u16 hb0[64 * 128];
    __shared__ u16 hb1[64 * 128];

    const int tid = threadIdx.x;
    const int w = tid >> 6, lane = tid & 63;
    const int l15 = lane & 15, g = lane >> 4;
    const int gbase = blockIdx.x * 64;
    const int j0 = w * 16 + g * 4;

    for (int i = tid; i < 64 * 128 / 2; i += 512) ((u32*)hb0)[i] = 0u;

    bf16x8 Ah[3][4], Ai[3];
#pragma unroll
    for (int a = 0; a < 3; ++a) {
        int gt = w + a * 8;
#pragma unroll
        for (int s = 0; s < 4; ++s)
            Ah[a][s] = *(const bf16x8*)(Ap + ((size_t)(gt * 4 + s) * 64 + lane) * 8);
        Ai[a] = *(const bf16x8*)(Aip + ((size_t)gt * 64 + lane) * 8);
    }

    f32x4 bnh4 = *(const f32x4*)(bhh + 256 + j0);
#pragma unroll
    for (int r = 0; r < 4; ++r) bnh4[r] *= S_N;

    const f32x4 fz = {0.f, 0.f, 0.f, 0.f};
    bf16x8 xdef;
    {
        uint4 u = make_uint4(0u, 0u, 0u, 0u);
        if (g == 2) u.x = 0x3F80u;
        *(uint4*)&xdef = u;
    }

    f32x4 hreg[4];
#pragma unroll
    for (int m = 0; m < 4; ++m) hreg[m] = fz;

    int xoff[4];
#pragma unroll
    for (int m = 0; m < 4; ++m) {
        int nd = gbase + m * 16 + l15;
        nd = nd < NND ? nd : NND - 1;
        xoff[m] = nd * (TT * FI) + g * 8;
    }

    __syncthreads();

    auto dostep = [&](int t, const u16* __restrict__ rb, u16* __restrict__ wb) {
#pragma unroll
        for (int mh = 0; mh < 2; ++mh) {
            const int ma = mh * 2, mb = mh * 2 + 1;
            bf16x8 xf0 = xdef, xf1 = xdef;
            if (g < 2) {
                xf0 = *(const bf16x8*)(xb + (size_t)(xoff[ma] + t * FI));
                xf1 = *(const bf16x8*)(xb + (size_t)(xoff[mb] + t * FI));
            }

            const int ra = ma * 16 + l15, rbr = mb * 16 + l15;
            bf16x8 b0[4], b1f[4];
#pragma unroll
            for (int s = 0; s < 4; ++s) {
                b0[s]  = *(const bf16x8*)&rb[hidx(ra, s * 32 + g * 8)];
                b1f[s] = *(const bf16x8*)&rb[hidx(rbr, s * 32 + g * 8)];
            }

            f32x4 acc[3][2], acci[2];
#pragma unroll
            for (int a = 0; a < 3; ++a) {
                acc[a][0] = __builtin_amdgcn_mfma_f32_16x16x32_bf16(Ah[a][0], b0[0], fz, 0, 0, 0);
                acc[a][1] = __builtin_amdgcn_mfma_f32_16x16x32_bf16(Ah[a][0], b1f[0], fz, 0, 0, 0);
            }
#pragma unroll
            for (int s = 1; s < 4; ++s) {
#pragma unroll
                for (int a = 0; a < 3; ++a) {
                    acc[a][0] = __builtin_amdgcn_mfma_f32_16x16x32_bf16(Ah[a][s], b0[s], acc[a][0], 0, 0, 0);
                    acc[a][1] = __builtin_amdgcn_mfma_f32_16x16x32_bf16(Ah[a][s], b1f[s], acc[a][1], 0, 0, 0);
                }
            }
            acc[0][0] = __builtin_amdgcn_mfma_f32_16x16x32_bf16(Ai[0], xf0, acc[0][0], 0, 0, 0);
            acc[1][0] = __builtin_amdgcn_mfma_f32_16x16x32_bf16(Ai[1], xf0, acc[1][0], 0, 0, 0);
            acci[0]   = __builtin_amdgcn_mfma_f32_16x16x32_bf16(Ai[2], xf0, fz, 0, 0, 0);
            acc[0][1] = __builtin_amdgcn_mfma_f32_16x16x32_bf16(Ai[0], xf1, acc[0][1], 0, 0, 0);
            acc[1][1] = __builtin_amdgcn_mfma_f32_16x16x32_bf16(Ai[1], xf1, acc[1][1], 0, 0, 0);
            acci[1]   = __builtin_amdgcn_mfma_f32_16x16x32_bf16(Ai[2], xf1, fz, 0, 0, 0);

#pragma unroll
            for (int mi = 0; mi < 2; ++mi) {
                int m = mh * 2 + mi;
#pragma unroll
                for (int r = 0; r < 4; ++r) {
                    float rr = __builtin_amdgcn_rcpf(1.0f + __builtin_amdgcn_exp2f(acc[0][mi][r]));
                    float zz = __builtin_amdgcn_rcpf(1.0f + __builtin_amdgcn_exp2f(acc[1][mi][r]));
                    float na = acci[mi][r] + rr * (acc[2][mi][r] + bnh4[r]);
                    float nn = 2.0f * __builtin_amdgcn_rcpf(1.0f + __builtin_amdgcn_exp2f(na)) - 1.0f;
                    float h = nn + zz * (hreg[m][r] - nn);
                    hreg[m][r] = h;
                }
                u32 p0 = cvtpk(hreg[m][0], hreg[m][1]);
                u32 p1 = cvtpk(hreg[m][2], hreg[m][3]);
                *(uint2*)&wb[hidx(m * 16 + l15, j0)] = make_uint2(p0, p1);
            }
        }
        __syncthreads();
    };

#pragma unroll 1
    for (int tt = 0; tt < TT; tt += 2) {
        dostep(tt, hb0, hb1);
        dostep(tt + 1, hb1, hb0);
    }
    // final h (bf16, swizzled) now lives in hb0; f32 copy in hreg.

    // ---- fused layer-1 dual projection ----
    bf16x8 Al[4], Ar[4];
#pragma unroll
    for (int s = 0; s < 4; ++s) {
        Al[s] = *(const bf16x8*)(Wl + ((size_t)(w * 4 + s) * 64 + lane) * 8);
        Ar[s] = *(const bf16x8*)(Wr + ((size_t)(w * 4 + s) * 64 + lane) * 8);
    }
    f32x4 bq = *(const f32x4*)(b1 + j0);

#pragma unroll
    for (int m = 0; m < 4; ++m) {
        bf16x8 b[4];
#pragma unroll
        for (int s = 0; s < 4; ++s)
            b[s] = *(const bf16x8*)&hb0[hidx(m * 16 + l15, s * 32 + g * 8)];
        f32x4 ap = fz, aq = fz;
#pragma unroll
        for (int s = 0; s < 4; ++s) {
            ap = __builtin_amdgcn_mfma_f32_16x16x32_bf16(Al[s], b[s], ap, 0, 0, 0);
            aq = __builtin_amdgcn_mfma_f32_16x16x32_bf16(Ar[s], b[s], aq, 0, 0, 0);
        }
        int nd = gbase + m * 16 + l15;
        if (nd < NND) {
            u32 c0 = cvtpk(ap[0], ap[1]), c1 = cvtpk(ap[2], ap[3]);
            *(uint2*)(P16 + (size_t)nd * HD + j0) = make_uint2(c0, c1);
            f32x4 v = aq + bq + hreg[m];
            *(f32x4*)(q + (size_t)nd * HD + j0) = v;
        }
    }
}

// ---------------- CSR construction ----------------
__global__ void count_kernel(const int* __restrict__ dst, int* __restrict__ cnt) {
    int e = blockIdx.x * 256 + threadIdx.x;
    if (e < NE) atomicAdd(&cnt[dst[e]], 1);
}

__global__ void blocksum_kernel(const int* __restrict__ cnt, int* __restrict__ bsum) {
    __shared__ int sh[256];
    int b = blockIdx.x, t = threadIdx.x;
    int base = b * 1024;
    int s = 0;
    for (int i = t; i < 1024; i += 256) {
        int idx = base + i;
        s += (idx < NND) ? cnt[idx] : 0;
    }
    sh[t] = s; __syncthreads();
    for (int o = 128; o > 0; o >>= 1) { if (t < o) sh[t] += sh[t + o]; __syncthreads(); }
    if (t == 0) bsum[b] = sh[0];
}

__global__ void scanbsum_kernel(int* __restrict__ bsum, int nb, int* __restrict__ rowptr) {
    if (threadIdx.x == 0 && blockIdx.x == 0) {
        int acc = 0;
        for (int i = 0; i < nb; ++i) { int v = bsum[i]; bsum[i] = acc; acc += v; }
        rowptr[NND] = NE;
    }
}

__global__ void scan_kernel(const int* __restrict__ cnt, const int* __restrict__ bsum,
                            int* __restrict__ rowptr) {
    __shared__ int sh[256];
    int b = blockIdx.x, t = threadIdx.x;
    int base = b * 1024;
    int v[4], loc = 0;
#pragma unroll
    for (int j = 0; j < 4; ++j) {
        int idx = base + t * 4 + j;
        v[j] = (idx < NND) ? cnt[idx] : 0;
        loc += v[j];
    }
    sh[t] = loc; __syncthreads();
    for (int o = 1; o < 256; o <<= 1) {
        int x = (t >= o) ? sh[t - o] : 0;
        __syncthreads();
        sh[t] += x;
        __syncthreads();
    }
    int acc = bsum[b] + sh[t] - loc;
#pragma unroll
    for (int j = 0; j < 4; ++j) {
        int idx = base + t * 4 + j;
        if (idx < NND) rowptr[idx] = acc;
        acc += v[j];
    }
}

// consumes cnt (counts -> 0); no separate fill array needed
__global__ void fill_kernel(const int* __restrict__ src, const int* __restrict__ dst,
                            const int* __restrict__ rowptr, int* __restrict__ cnt,
                            int* __restrict__ csr) {
    int e = blockIdx.x * 256 + threadIdx.x;
    if (e >= NE) return;
    int d = dst[e];
    int off = atomicSub(&cnt[d], 1) - 1;
    csr[rowptr[d] + off] = src[e];
}

// ---------------- fused gather (layer1 mean+relu) + layer-2 dual projection ----------------
__global__ __launch_bounds__(512) void gather_proj_kernel(
    const u16* __restrict__ P16,     // [N][128] bf16 messages
    const int* __restrict__ rowptr, const int* __restrict__ csr,
    const float* __restrict__ q,     // [N][128] f32 self-path
    const u16* __restrict__ W2l, const u16* __restrict__ W2r,
    const float* __restrict__ b2,
    u16* __restrict__ P2,            // [N][64] bf16
    float* __restrict__ q2)          // [N][64] f32
{
    __shared__ u16 xs[64 * 128];

    const int tid = threadIdx.x;
    const int w = tid >> 6, lane = tid & 63;
    const int l15 = lane & 15, g = lane >> 4;
    const int gbase = blockIdx.x * 64;
    const f32x4 fz = {0.f, 0.f, 0.f, 0.f};

    // phase 1: each wave gathers 8 nodes; 4-deep load batching for MLP
#pragma unroll 1
    for (int i = 0; i < 8; ++i) {
        int nloc = w * 8 + i;
        int n = gbase + nloc;
        u32 gv = 0u;
        if (n < NND) {
            int beg = rowptr[n], end = rowptr[n + 1];
            float ax = 0.f, ay = 0.f;
            for (int cb = beg; cb < end; cb += 64) {
                int myi = (cb + lane < end) ? csr[cb + lane] : 0;
                int nn = min(end - cb, 64);
                int ii = 0;
                for (; ii + 4 <= nn; ii += 4) {
                    int s0 = __shfl(myi, ii + 0), s1 = __shfl(myi, ii + 1);
                    int s2 = __shfl(myi, ii + 2), s3 = __shfl(myi, ii + 3);
                    u32 p0 = *(const u32*)(P16 + (size_t)s0 * HD + lane * 2);
                    u32 p1 = *(const u32*)(P16 + (size_t)s1 * HD + lane * 2);
                    u32 p2 = *(const u32*)(P16 + (size_t)s2 * HD + lane * 2);
                    u32 p3 = *(const u32*)(P16 + (size_t)s3 * HD + lane * 2);
                    ax += b2f((u16)p0) + b2f((u16)p1) + b2f((u16)p2) + b2f((u16)p3);
                    ay += b2f((u16)(p0 >> 16)) + b2f((u16)(p1 >> 16)) +
                          b2f((u16)(p2 >> 16)) + b2f((u16)(p3 >> 16));
                }
                for (; ii < nn; ++ii) {
                    int s = __shfl(myi, ii);
                    u32 pv = *(const u32*)(P16 + (size_t)s * HD + lane * 2);
                    ax += b2f((u16)pv); ay += b2f((u16)(pv >> 16));
                }
            }
            int deg = end - beg;
            float inv = 1.0f / (float)(deg > 0 ? deg : 1);
            float2 qv = *(const float2*)(q + (size_t)n * HD + lane * 2);
            gv = cvtpk(fmaxf(ax * inv + qv.x, 0.f), fmaxf(ay * inv + qv.y, 0.f));
        }
        *(u32*)&xs[hidx(nloc, lane * 2)] = gv;
    }
    __syncthreads();

    // phase 2: M=64 dual projection (waves 0-3 -> P2, 4-7 -> Q2)
    const int tile = w & 3;
    const bool isQ = (w >= 4);
    const u16* Wsel = isQ ? W2r : W2l;
    bf16x8 A[4];
#pragma unroll
    for (int s = 0; s < 4; ++s)
        A[s] = *(const bf16x8*)(Wsel + ((size_t)(tile * 4 + s) * 64 + lane) * 8);
    const int f0 = tile * 16 + g * 4;
    f32x4 bq = *(const f32x4*)(b2 + f0);

#pragma unroll
    for (int m = 0; m < 4; ++m) {
        bf16x8 b[4];
#pragma unroll
        for (int s = 0; s < 4; ++s)
            b[s] = *(const bf16x8*)&xs[hidx(m * 16 + l15, s * 32 + g * 8)];
        f32x4 a = fz;
#pragma unroll
        for (int s = 0; s < 4; ++s)
            a = __builtin_amdgcn_mfma_f32_16x16x32_bf16(A[s], b[s], a, 0, 0, 0);
        int nd = gbase + m * 16 + l15;
        if (nd < NND) {
            if (isQ) {
                f32x4 v = a + bq;
                *(f32x4*)(q2 + (size_t)nd * OD + f0) = v;
            } else {
                u32 c0 = cvtpk(a[0], a[1]), c1 = cvtpk(a[2], a[3]);
                *(uint2*)(P2 + (size_t)nd * OD + f0) = make_uint2(c0, c1);
            }
        }
    }
}

// ---------------- final gather (layer2 mean), 4-deep load batching ----------------
__global__ __launch_bounds__(256) void gather2_kernel(
    const u16* __restrict__ P2,      // [N][64] bf16
    const int* __restrict__ rowptr, const int* __restrict__ csr,
    const float* __restrict__ q2,    // [N][64] f32
    float* __restrict__ outp)        // [N][64] f32
{
    int n = ((blockIdx.x * 256 + threadIdx.x) >> 6);
    if (n >= NND) return;
    int lane = threadIdx.x & 63;
    int beg = rowptr[n], end = rowptr[n + 1];

    float a = 0.f;
    for (int cb = beg; cb < end; cb += 64) {
        int myi = (cb + lane < end) ? csr[cb + lane] : 0;
        int nn = min(end - cb, 64);
        int i = 0;
        for (; i + 4 <= nn; i += 4) {
            int s0 = __shfl(myi, i + 0), s1 = __shfl(myi, i + 1);
            int s2 = __shfl(myi, i + 2), s3 = __shfl(myi, i + 3);
            u16 v0 = P2[(size_t)s0 * OD + lane];
            u16 v1 = P2[(size_t)s1 * OD + lane];
            u16 v2 = P2[(size_t)s2 * OD + lane];
            u16 v3 = P2[(size_t)s3 * OD + lane];
            a += b2f(v0) + b2f(v1) + b2f(v2) + b2f(v3);
        }
        for (; i < nn; ++i) {
            int s = __shfl(myi, i);
            a += b2f(P2[(size_t)s * OD + lane]);
        }
    }
    int deg = end - beg;
    float inv = 1.0f / (float)(deg > 0 ? deg : 1);
    outp[(size_t)n * OD + lane] = a * inv + q2[(size_t)n * OD + lane];
}

// ---------------- launch ----------------
extern "C" void kernel_launch(void* const* d_in, const int* in_sizes, int n_in,
                              void* d_out, int out_size, void* d_ws, size_t ws_size,
                              hipStream_t stream) {
    const float* x   = (const float*)d_in[0];
    const int*   edg = (const int*)d_in[1];
    const int*   src = edg;
    const int*   dst = edg + NE;
    const float* Wih = (const float*)d_in[2];
    const float* Whh = (const float*)d_in[3];
    const float* bih = (const float*)d_in[4];
    const float* bhh = (const float*)d_in[5];
    const float* W1l = (const float*)d_in[6];
    const float* b1  = (const float*)d_in[7];
    const float* W1r = (const float*)d_in[8];
    const float* W2l = (const float*)d_in[9];
    const float* b2  = (const float*)d_in[10];
    const float* W2r = (const float*)d_in[11];
    float* out = (float*)d_out;

    char* wsp = (char*)d_ws;
    auto alloc = [&](size_t nbytes) {
        char* p = wsp; wsp += (nbytes + 255) & ~(size_t)255; return p;
    };
    u16*   Ap    = (u16*)alloc((size_t)6144 * 8 * 2);
    u16*   Aip   = (u16*)alloc((size_t)1536 * 8 * 2);
    u16*   Pw1l  = (u16*)alloc((size_t)2048 * 8 * 2);
    u16*   Pw1r  = (u16*)alloc((size_t)2048 * 8 * 2);
    u16*   Pw2l  = (u16*)alloc((size_t)1024 * 8 * 2);
    u16*   Pw2r  = (u16*)alloc((size_t)1024 * 8 * 2);
    int*   cnt   = (int*)alloc((size_t)NND * 4);
    int*   rowp  = (int*)alloc((size_t)(NND + 1) * 4);
    int*   bsum  = (int*)alloc((size_t)128 * 4);
    int*   csr   = (int*)alloc((size_t)NE * 4);
    u16*   xb    = (u16*)alloc((size_t)NND * TT * FI * 2);
    float* q     = (float*)alloc((size_t)NND * HD * 4);
    u16*   P16   = (u16*)alloc((size_t)NND * HD * 2);
    u16*   P2    = (u16*)alloc((size_t)NND * OD * 2);
    float* q2    = (float*)alloc((size_t)NND * OD * 4);

    const int NB_SCAN = (NND + 1023) / 1024;

    hipMemsetAsync(cnt, 0, (size_t)NND * 4, stream);

    // prep
    cvt_x_kernel<<<(NND * TT * FI) / (256 * 8), 256, 0, stream>>>(x, xb);
    pack_w_kernel<<<30, 256, 0, stream>>>(Whh, Wih, bih, bhh, Ap, Aip);
    pack_gemm_kernel<<<8, 256, 0, stream>>>(W1l, Pw1l, HD);
    pack_gemm_kernel<<<8, 256, 0, stream>>>(W1r, Pw1r, HD);
    pack_gemm_kernel<<<4, 256, 0, stream>>>(W2l, Pw2l, OD);
    pack_gemm_kernel<<<4, 256, 0, stream>>>(W2r, Pw2r, OD);

    // CSR build
    count_kernel<<<(NE + 255) / 256, 256, 0, stream>>>(dst, cnt);
    blocksum_kernel<<<NB_SCAN, 256, 0, stream>>>(cnt, bsum);
    scanbsum_kernel<<<1, 64, 0, stream>>>(bsum, NB_SCAN, rowp);
    scan_kernel<<<NB_SCAN, 256, 0, stream>>>(cnt, bsum, rowp);
    fill_kernel<<<(NE + 255) / 256, 256, 0, stream>>>(src, dst, rowp, cnt, csr);

    // GRU + fused layer-1 projection -> P16 (bf16), q (f32, bias+residual)
    const int nblk = (NND + 63) / 64;
    gru_mfma_kernel<<<nblk, 512, 0, stream>>>(xb, Ap, Aip, bhh, Pw1l, Pw1r, b1, P16, q);

    // gather layer-1 (+relu) fused with layer-2 projection -> P2, q2
    gather_proj_kernel<<<nblk, 512, 0, stream>>>(P16, rowp, csr, q, Pw2l, Pw2r, b2, P2, q2);

    // final mean-gather -> out
    gather2_kernel<<<(NND * 64 + 255) / 256, 256, 0, stream>>>(P2, rowp, csr, q2, out);
}